// Round 1
// baseline (1115.470 us; speedup 1.0000x reference)
//
#include <hip/hip_runtime.h>
#include <cstddef>

// ---------------------------------------------------------------------------
// Mamba block forward, fp32 correctness-first pipeline.
// B=2, L=1024, D=1024, ED=2048, N=16, R=64, K=4.  BL = B*L = 2048.
// ---------------------------------------------------------------------------

#define BL   2048
#define DIM  1024
#define ED   2048
#define NST  16
#define RLOW 64

__device__ __forceinline__ float silu_(float x) {
  return x / (1.f + __expf(-x));
}

// C[M,N] = A[M,K] @ W[N,K]^T (+bias) (+softplus if ACT==1)
// A row-major (lda = row stride), W row-major (ldw = row stride), both K-contig.
// Grid: (M/64, ceil(N/64)), block 256. M must be a multiple of 64; K of 16.
template <int ACT>
__global__ __launch_bounds__(256) void gemm_nt(
    const float* __restrict__ A, int lda,
    const float* __restrict__ W, int ldw,
    const float* __restrict__ bias,
    float* __restrict__ C, int ldc,
    int N, int K)
{
  __shared__ float As[16][64];
  __shared__ float Ws[16][64];
  const int tid = threadIdx.x;
  const int bm = blockIdx.x * 64;
  const int bn = blockIdx.y * 64;
  const int tx = tid & 15;        // 0..15  -> 4 cols each
  const int ty = tid >> 4;        // 0..15  -> 4 rows each
  const int srow = tid >> 2;      // 0..63  staging row
  const int scg  = (tid & 3) * 4; // staging k-chunk

  float acc[4][4] = {};

  const float* Aptr = A + (size_t)(bm + srow) * lda + scg;
  const bool   wok  = (bn + srow) < N;
  const float* Wptr = W + (size_t)(bn + srow) * ldw + scg;

  for (int k0 = 0; k0 < K; k0 += 16) {
    float4 av = *(const float4*)(Aptr + k0);
    float4 wv = make_float4(0.f, 0.f, 0.f, 0.f);
    if (wok) wv = *(const float4*)(Wptr + k0);
    __syncthreads();
    As[scg + 0][srow] = av.x; As[scg + 1][srow] = av.y;
    As[scg + 2][srow] = av.z; As[scg + 3][srow] = av.w;
    Ws[scg + 0][srow] = wv.x; Ws[scg + 1][srow] = wv.y;
    Ws[scg + 2][srow] = wv.z; Ws[scg + 3][srow] = wv.w;
    __syncthreads();
#pragma unroll
    for (int k = 0; k < 16; ++k) {
      float4 a4 = *(const float4*)&As[k][ty * 4];
      float4 w4 = *(const float4*)&Ws[k][tx * 4];
      float a_[4] = {a4.x, a4.y, a4.z, a4.w};
      float w_[4] = {w4.x, w4.y, w4.z, w4.w};
#pragma unroll
      for (int i = 0; i < 4; ++i)
#pragma unroll
        for (int j = 0; j < 4; ++j)
          acc[i][j] += a_[i] * w_[j];
    }
  }

#pragma unroll
  for (int i = 0; i < 4; ++i) {
    const int row = bm + ty * 4 + i;
#pragma unroll
    for (int j = 0; j < 4; ++j) {
      const int col = bn + tx * 4 + j;
      if (col < N) {
        float v = acc[i][j];
        if (bias) v += bias[col];
        if (ACT == 1) v = (v > 20.f) ? v : log1pf(__expf(v));
        C[(size_t)row * ldc + col] = v;
      }
    }
  }
}

// causal depthwise conv (K=4) + bias + SiLU.
// xz: (BL, 2*ED) row-major; channels 0..ED-1 are the conv input.
// xc out: (BL, ED).  One thread per (row, 4 channels).
__global__ __launch_bounds__(256) void conv_silu_k(
    const float* __restrict__ xz, const float* __restrict__ cw,
    const float* __restrict__ cb, float* __restrict__ xc)
{
  const int idx = blockIdx.x * 256 + threadIdx.x;   // BL * ED/4 = 1,048,576
  const int row = idx >> 9;                         // 0..2047
  const int e   = (idx & 511) * 4;
  const int l   = row & 1023;
  const float* base = xz + (size_t)(row - l) * (2 * ED) + e;  // batch start, col e

  float4 acc = *(const float4*)(cb + e);
#pragma unroll
  for (int k = 0; k < 4; ++k) {
    const int ls = l - 3 + k;
    if (ls >= 0) {
      float4 v = *(const float4*)(base + (size_t)ls * (2 * ED));
      acc.x += cw[(size_t)(e + 0) * 4 + k] * v.x;
      acc.y += cw[(size_t)(e + 1) * 4 + k] * v.y;
      acc.z += cw[(size_t)(e + 2) * 4 + k] * v.z;
      acc.w += cw[(size_t)(e + 3) * 4 + k] * v.w;
    }
  }
  acc.x = silu_(acc.x); acc.y = silu_(acc.y);
  acc.z = silu_(acc.z); acc.w = silu_(acc.w);
  *(float4*)(xc + (size_t)row * ED + e) = acc;
}

// Selective scan. 16 lanes per (b,e) pair covering n=0..15.
// h_t = exp(dt*A[e,n]) * h_{t-1} + (dt*xc)*B[b,l,n];  y = sum_n C*h + D*xc
// fused with z-gate: yg = (y) * silu(z).
__global__ __launch_bounds__(256) void scan_k(
    const float* __restrict__ dt,    // (BL, ED)
    const float* __restrict__ xc,    // (BL, ED)
    const float* __restrict__ dbc,   // (BL, 96): [0:64) dt_raw, [64:80) B, [80:96) C
    const float* __restrict__ A_log, // (ED, 16)
    const float* __restrict__ Dp,    // (ED)
    const float* __restrict__ xz,    // (BL, 2*ED) -> z = cols [ED, 2*ED)
    float* __restrict__ yg)          // (BL, ED)
{
  const int tid  = threadIdx.x;
  const int n    = tid & 15;
  const int g    = tid >> 4;                  // 16 groups / block
  const int pair = blockIdx.x * 16 + g;       // 0..4095
  const int b    = pair >> 11;
  const int e    = pair & (ED - 1);

  const float Aen = -__expf(A_log[(size_t)e * NST + n]);
  const float De  = Dp[e];
  const size_t rowbase = (size_t)b * 1024;

  float h = 0.f;
  // prefetch l=0
  size_t r = rowbase;
  float dtv = dt[r * ED + e];
  float xcv = xc[r * ED + e];
  float Bv  = dbc[r * 96 + RLOW + n];
  float Cv  = dbc[r * 96 + RLOW + NST + n];

  for (int l = 0; l < 1024; ++l) {
    const float dtc = dtv, xcc = xcv, Bc = Bv, Cc = Cv;
    if (l < 1023) {
      const size_t r2 = rowbase + l + 1;
      dtv = dt[r2 * ED + e];
      xcv = xc[r2 * ED + e];
      Bv  = dbc[r2 * 96 + RLOW + n];
      Cv  = dbc[r2 * 96 + RLOW + NST + n];
    }
    const float dA = __expf(dtc * Aen);
    h = dA * h + (dtc * xcc) * Bc;
    float c = Cc * h;
    c += __shfl_xor(c, 1);
    c += __shfl_xor(c, 2);
    c += __shfl_xor(c, 4);
    c += __shfl_xor(c, 8);
    if (n == 0) {
      const size_t rr = rowbase + l;
      const float y  = c + De * xcc;
      const float zv = xz[rr * (2 * ED) + ED + e];
      yg[rr * ED + e] = y * silu_(zv);
    }
  }
}

extern "C" void kernel_launch(void* const* d_in, const int* in_sizes, int n_in,
                              void* d_out, int out_size, void* d_ws, size_t ws_size,
                              hipStream_t stream) {
  const float* x         = (const float*)d_in[0];   // (2,1024,1024)
  const float* in_w      = (const float*)d_in[1];   // (4096,1024)
  const float* in_b      = (const float*)d_in[2];   // (4096)
  const float* conv_w    = (const float*)d_in[3];   // (2048,1,4)
  const float* conv_b    = (const float*)d_in[4];   // (2048)
  const float* xproj_w   = (const float*)d_in[5];   // (96,2048)
  const float* dtproj_w  = (const float*)d_in[6];   // (2048,64)
  const float* dtproj_b  = (const float*)d_in[7];   // (2048)
  const float* A_log     = (const float*)d_in[8];   // (2048,16)
  const float* D_param   = (const float*)d_in[9];   // (2048)
  const float* outproj_w = (const float*)d_in[10];  // (1024,2048)
  float* out = (float*)d_out;

  float* ws  = (float*)d_ws;
  float* xz  = ws;                 // BL*4096       = 8,388,608 f (32 MB)
  float* xc  = xz  + 8388608;      // BL*2048       = 4,194,304 f (16 MB)
  float* dbc = xc  + 4194304;      // BL*96         =   196,608 f
  float* dtb = dbc + 196608;       // BL*2048       = 4,194,304 f
  float* yg  = dtb + 4194304;      // BL*2048       = 4,194,304 f
  // total ~21.2M floats ~ 85 MB

  const dim3 blk(256);

  // 1) xz = x @ in_proj_w^T + b          (2048 x 4096, K=1024)
  gemm_nt<0><<<dim3(BL / 64, 4096 / 64), blk, 0, stream>>>(
      x, DIM, in_w, DIM, in_b, xz, 2 * ED, 2 * ED, DIM);

  // 2) xc = silu(causal_conv(xz[:, :ED]) + conv_b)
  conv_silu_k<<<dim3((BL * (ED / 4)) / 256), blk, 0, stream>>>(xz, conv_w, conv_b, xc);

  // 3) dbc = xc @ x_proj_w^T             (2048 x 96, K=2048)
  gemm_nt<0><<<dim3(BL / 64, 2), blk, 0, stream>>>(
      xc, ED, xproj_w, ED, nullptr, dbc, 96, 96, ED);

  // 4) dt = softplus(dbc[:, :64] @ dt_proj_w^T + dt_proj_b)   (2048 x 2048, K=64)
  gemm_nt<1><<<dim3(BL / 64, ED / 64), blk, 0, stream>>>(
      dbc, 96, dtproj_w, RLOW, dtproj_b, dtb, ED, ED, RLOW);

  // 5) selective scan + gate: yg = (scan_y + D*xc) * silu(z)
  scan_k<<<dim3(256), blk, 0, stream>>>(dtb, xc, dbc, A_log, D_param, xz, yg);

  // 6) out = yg @ out_proj_w^T           (2048 x 1024, K=2048)
  gemm_nt<0><<<dim3(BL / 64, DIM / 64), blk, 0, stream>>>(
      yg, ED, outproj_w, ED, nullptr, out, DIM, DIM, ED);
}

// Round 2
// 645.397 us; speedup vs baseline: 1.7283x; 1.7283x over previous
//
#include <hip/hip_runtime.h>
#include <cstddef>

// ---------------------------------------------------------------------------
// Mamba block forward. B=2, L=1024, D=1024, ED=2048, N=16, R=64, K=4. BL=2048.
// Round 2: chunked parallel selective scan (3 kernels) replaces serial scan_k.
// ---------------------------------------------------------------------------

#define BL   2048
#define DIM  1024
#define ED   2048
#define NST  16
#define RLOW 64
#define CH   32   // chunks per sequence
#define LC   32   // timesteps per chunk (CH*LC = L = 1024)

__device__ __forceinline__ float silu_(float x) {
  return x / (1.f + __expf(-x));
}

// C[M,N] = A[M,K] @ W[N,K]^T (+bias) (+softplus if ACT==1)
template <int ACT>
__global__ __launch_bounds__(256) void gemm_nt(
    const float* __restrict__ A, int lda,
    const float* __restrict__ W, int ldw,
    const float* __restrict__ bias,
    float* __restrict__ C, int ldc,
    int N, int K)
{
  __shared__ float As[16][64];
  __shared__ float Ws[16][64];
  const int tid = threadIdx.x;
  const int bm = blockIdx.x * 64;
  const int bn = blockIdx.y * 64;
  const int tx = tid & 15;
  const int ty = tid >> 4;
  const int srow = tid >> 2;
  const int scg  = (tid & 3) * 4;

  float acc[4][4] = {};

  const float* Aptr = A + (size_t)(bm + srow) * lda + scg;
  const bool   wok  = (bn + srow) < N;
  const float* Wptr = W + (size_t)(bn + srow) * ldw + scg;

  for (int k0 = 0; k0 < K; k0 += 16) {
    float4 av = *(const float4*)(Aptr + k0);
    float4 wv = make_float4(0.f, 0.f, 0.f, 0.f);
    if (wok) wv = *(const float4*)(Wptr + k0);
    __syncthreads();
    As[scg + 0][srow] = av.x; As[scg + 1][srow] = av.y;
    As[scg + 2][srow] = av.z; As[scg + 3][srow] = av.w;
    Ws[scg + 0][srow] = wv.x; Ws[scg + 1][srow] = wv.y;
    Ws[scg + 2][srow] = wv.z; Ws[scg + 3][srow] = wv.w;
    __syncthreads();
#pragma unroll
    for (int k = 0; k < 16; ++k) {
      float4 a4 = *(const float4*)&As[k][ty * 4];
      float4 w4 = *(const float4*)&Ws[k][tx * 4];
      float a_[4] = {a4.x, a4.y, a4.z, a4.w};
      float w_[4] = {w4.x, w4.y, w4.z, w4.w};
#pragma unroll
      for (int i = 0; i < 4; ++i)
#pragma unroll
        for (int j = 0; j < 4; ++j)
          acc[i][j] += a_[i] * w_[j];
    }
  }

#pragma unroll
  for (int i = 0; i < 4; ++i) {
    const int row = bm + ty * 4 + i;
#pragma unroll
    for (int j = 0; j < 4; ++j) {
      const int col = bn + tx * 4 + j;
      if (col < N) {
        float v = acc[i][j];
        if (bias) v += bias[col];
        if (ACT == 1) v = (v > 20.f) ? v : log1pf(__expf(v));
        C[(size_t)row * ldc + col] = v;
      }
    }
  }
}

// causal depthwise conv (K=4) + bias + SiLU.
__global__ __launch_bounds__(256) void conv_silu_k(
    const float* __restrict__ xz, const float* __restrict__ cw,
    const float* __restrict__ cb, float* __restrict__ xc)
{
  const int idx = blockIdx.x * 256 + threadIdx.x;
  const int row = idx >> 9;
  const int e   = (idx & 511) * 4;
  const int l   = row & 1023;
  const float* base = xz + (size_t)(row - l) * (2 * ED) + e;

  float4 acc = *(const float4*)(cb + e);
#pragma unroll
  for (int k = 0; k < 4; ++k) {
    const int ls = l - 3 + k;
    if (ls >= 0) {
      float4 v = *(const float4*)(base + (size_t)ls * (2 * ED));
      acc.x += cw[(size_t)(e + 0) * 4 + k] * v.x;
      acc.y += cw[(size_t)(e + 1) * 4 + k] * v.y;
      acc.z += cw[(size_t)(e + 2) * 4 + k] * v.z;
      acc.w += cw[(size_t)(e + 3) * 4 + k] * v.w;
    }
  }
  acc.x = silu_(acc.x); acc.y = silu_(acc.y);
  acc.z = silu_(acc.z); acc.w = silu_(acc.w);
  *(float4*)(xc + (size_t)row * ED + e) = acc;
}

// ---------------- chunked selective scan ----------------
// Phase 1: per (b, chunk, e) thread, all 16 states in registers.
// Emits composed (prod dA, local b) per n for the chunk.
// Layout of aprod/bfin: [((b*ED + e)*CH + c)*16 + n]
__global__ __launch_bounds__(256) void scan_phase1(
    const float* __restrict__ dt,    // (BL, ED)
    const float* __restrict__ xc,    // (BL, ED)
    const float* __restrict__ dbc,   // (BL, 96)
    const float* __restrict__ A_log, // (ED, 16)
    float* __restrict__ aprod_o,
    float* __restrict__ bfin_o)
{
  const int tid = blockIdx.x * 256 + threadIdx.x;   // 131072 = B*CH*ED
  const int e  = tid & (ED - 1);
  const int bc = tid >> 11;
  const int b  = bc >> 5;
  const int c  = bc & (CH - 1);

  float Aen[NST];
  {
    const float4* Ap = (const float4*)(A_log + (size_t)e * NST);
#pragma unroll
    for (int q = 0; q < 4; ++q) {
      float4 v = Ap[q];
      Aen[q * 4 + 0] = -__expf(v.x); Aen[q * 4 + 1] = -__expf(v.y);
      Aen[q * 4 + 2] = -__expf(v.z); Aen[q * 4 + 3] = -__expf(v.w);
    }
  }

  float h[NST], ap[NST];
#pragma unroll
  for (int n = 0; n < NST; ++n) { h[n] = 0.f; ap[n] = 1.f; }

  const size_t rowbase = (size_t)b * 1024 + (size_t)c * LC;
  for (int i = 0; i < LC; ++i) {
    const size_t rr = rowbase + i;
    const float dtv = dt[rr * ED + e];
    const float xcv = xc[rr * ED + e];
    const float dx  = dtv * xcv;
    float Bv[NST];
    {
      const float4* Bp = (const float4*)(dbc + rr * 96 + RLOW);
#pragma unroll
      for (int q = 0; q < 4; ++q) { float4 v = Bp[q];
        Bv[q*4+0]=v.x; Bv[q*4+1]=v.y; Bv[q*4+2]=v.z; Bv[q*4+3]=v.w; }
    }
#pragma unroll
    for (int n = 0; n < NST; ++n) {
      const float dA = __expf(dtv * Aen[n]);
      ap[n] *= dA;
      h[n] = dA * h[n] + dx * Bv[n];
    }
  }

  float* ao = aprod_o + ((size_t)((b * ED + e) * CH + c)) * NST;
  float* bo = bfin_o  + ((size_t)((b * ED + e) * CH + c)) * NST;
#pragma unroll
  for (int q = 0; q < 4; ++q) {
    ((float4*)ao)[q] = make_float4(ap[q*4+0], ap[q*4+1], ap[q*4+2], ap[q*4+3]);
    ((float4*)bo)[q] = make_float4(h[q*4+0],  h[q*4+1],  h[q*4+2],  h[q*4+3]);
  }
}

// Phase 2: per (b,e,n) thread, serial scan over CH chunk summaries.
// Overwrites bfin[c] with the chunk's STARTING state.
__global__ __launch_bounds__(256) void scan_phase2(
    const float* __restrict__ aprod, float* __restrict__ bfin)
{
  const int tid = blockIdx.x * 256 + threadIdx.x;   // 65536 = B*ED*NST
  const int n  = tid & (NST - 1);
  const int be = tid >> 4;
  const size_t base = (size_t)be * CH * NST + n;
  float hs = 0.f;
  for (int c = 0; c < CH; ++c) {
    const size_t idx = base + (size_t)c * NST;
    const float a  = aprod[idx];
    const float bf = bfin[idx];
    bfin[idx] = hs;
    hs = a * hs + bf;
  }
}

// Phase 3: recompute chunk recurrence from known start state; emit gated y.
__global__ __launch_bounds__(256) void scan_phase3(
    const float* __restrict__ dt,
    const float* __restrict__ xc,
    const float* __restrict__ dbc,
    const float* __restrict__ A_log,
    const float* __restrict__ Dp,
    const float* __restrict__ xz,    // z = cols [ED, 2*ED)
    const float* __restrict__ hst,   // per-chunk start states (bfin)
    float* __restrict__ yg)
{
  const int tid = blockIdx.x * 256 + threadIdx.x;
  const int e  = tid & (ED - 1);
  const int bc = tid >> 11;
  const int b  = bc >> 5;
  const int c  = bc & (CH - 1);

  float Aen[NST];
  {
    const float4* Ap = (const float4*)(A_log + (size_t)e * NST);
#pragma unroll
    for (int q = 0; q < 4; ++q) {
      float4 v = Ap[q];
      Aen[q * 4 + 0] = -__expf(v.x); Aen[q * 4 + 1] = -__expf(v.y);
      Aen[q * 4 + 2] = -__expf(v.z); Aen[q * 4 + 3] = -__expf(v.w);
    }
  }

  float h[NST];
  {
    const float4* Hp = (const float4*)(hst + ((size_t)((b * ED + e) * CH + c)) * NST);
#pragma unroll
    for (int q = 0; q < 4; ++q) { float4 v = Hp[q];
      h[q*4+0]=v.x; h[q*4+1]=v.y; h[q*4+2]=v.z; h[q*4+3]=v.w; }
  }

  const float De = Dp[e];
  const size_t rowbase = (size_t)b * 1024 + (size_t)c * LC;
  for (int i = 0; i < LC; ++i) {
    const size_t rr = rowbase + i;
    const float dtv = dt[rr * ED + e];
    const float xcv = xc[rr * ED + e];
    const float dx  = dtv * xcv;
    float Bv[NST], Cv[NST];
    {
      const float4* Bp = (const float4*)(dbc + rr * 96 + RLOW);
      const float4* Cp = (const float4*)(dbc + rr * 96 + RLOW + NST);
#pragma unroll
      for (int q = 0; q < 4; ++q) {
        float4 v = Bp[q];
        Bv[q*4+0]=v.x; Bv[q*4+1]=v.y; Bv[q*4+2]=v.z; Bv[q*4+3]=v.w;
        float4 w = Cp[q];
        Cv[q*4+0]=w.x; Cv[q*4+1]=w.y; Cv[q*4+2]=w.z; Cv[q*4+3]=w.w;
      }
    }
    float y = 0.f;
#pragma unroll
    for (int n = 0; n < NST; ++n) {
      const float dA = __expf(dtv * Aen[n]);
      h[n] = dA * h[n] + dx * Bv[n];
      y += Cv[n] * h[n];
    }
    y += De * xcv;
    const float zv = xz[rr * (2 * ED) + ED + e];
    yg[rr * ED + e] = y * silu_(zv);
  }
}

extern "C" void kernel_launch(void* const* d_in, const int* in_sizes, int n_in,
                              void* d_out, int out_size, void* d_ws, size_t ws_size,
                              hipStream_t stream) {
  const float* x         = (const float*)d_in[0];
  const float* in_w      = (const float*)d_in[1];
  const float* in_b      = (const float*)d_in[2];
  const float* conv_w    = (const float*)d_in[3];
  const float* conv_b    = (const float*)d_in[4];
  const float* xproj_w   = (const float*)d_in[5];
  const float* dtproj_w  = (const float*)d_in[6];
  const float* dtproj_b  = (const float*)d_in[7];
  const float* A_log     = (const float*)d_in[8];
  const float* D_param   = (const float*)d_in[9];
  const float* outproj_w = (const float*)d_in[10];
  float* out = (float*)d_out;

  float* ws    = (float*)d_ws;
  float* xz    = ws;                  // 8,388,608 f
  float* xc    = xz    + 8388608;     // 4,194,304 f
  float* dbc   = xc    + 4194304;     //   196,608 f
  float* dtb   = dbc   + 196608;      // 4,194,304 f
  float* yg    = dtb   + 4194304;     // 4,194,304 f
  float* aprod = yg    + 4194304;     // 2,097,152 f  (B*ED*CH*NST)
  float* bfin  = aprod + 2097152;     // 2,097,152 f
  // total 25,362,432 floats ~ 101.4 MB

  const dim3 blk(256);

  // 1) xz = x @ in_proj_w^T + b
  gemm_nt<0><<<dim3(BL / 64, 4096 / 64), blk, 0, stream>>>(
      x, DIM, in_w, DIM, in_b, xz, 2 * ED, 2 * ED, DIM);

  // 2) xc = silu(causal_conv(xz[:, :ED]) + conv_b)
  conv_silu_k<<<dim3((BL * (ED / 4)) / 256), blk, 0, stream>>>(xz, conv_w, conv_b, xc);

  // 3) dbc = xc @ x_proj_w^T
  gemm_nt<0><<<dim3(BL / 64, 2), blk, 0, stream>>>(
      xc, ED, xproj_w, ED, nullptr, dbc, 96, 96, ED);

  // 4) dt = softplus(dbc[:, :64] @ dt_proj_w^T + dt_proj_b)
  gemm_nt<1><<<dim3(BL / 64, ED / 64), blk, 0, stream>>>(
      dbc, 96, dtproj_w, RLOW, dtproj_b, dtb, ED, ED, RLOW);

  // 5) chunked scan
  scan_phase1<<<dim3((2 * CH * ED) / 256), blk, 0, stream>>>(
      dtb, xc, dbc, A_log, aprod, bfin);
  scan_phase2<<<dim3((2 * ED * NST) / 256), blk, 0, stream>>>(aprod, bfin);
  scan_phase3<<<dim3((2 * CH * ED) / 256), blk, 0, stream>>>(
      dtb, xc, dbc, A_log, D_param, xz, bfin, yg);

  // 6) out = yg @ out_proj_w^T
  gemm_nt<0><<<dim3(BL / 64, DIM / 64), blk, 0, stream>>>(
      yg, ED, outproj_w, ED, nullptr, out, DIM, DIM, ED);
}

// Round 6
// 286.722 us; speedup vs baseline: 3.8904x; 2.2509x over previous
//
#include <hip/hip_runtime.h>
#include <cstddef>

// ---------------------------------------------------------------------------
// Mamba block forward. B=2, L=1024, D=1024, ED=2048, N=16, R=64, K=4. BL=2048.
// Round 6: resubmit of round-4 (two infra failures) — fixed gemm_bf16 staging.
// ---------------------------------------------------------------------------

#define BL   2048
#define DIM  1024
#define ED   2048
#define NST  16
#define RLOW 64
#define CH   32
#define LC   32

typedef __attribute__((ext_vector_type(4))) float   f32x4;
typedef __attribute__((ext_vector_type(8))) __bf16  bf16x8;
typedef __attribute__((ext_vector_type(8))) unsigned short us8;

__device__ __forceinline__ float silu_(float x) {
  return x / (1.f + __expf(-x));
}

__device__ __forceinline__ unsigned short f2b(float x) {
  union { float f; unsigned int u; } v; v.f = x;
  unsigned int r = v.u + 0x7FFFu + ((v.u >> 16) & 1u);   // RNE
  return (unsigned short)(r >> 16);
}

__device__ __forceinline__ f32x4 mfma_bf16(us8 a, us8 b, f32x4 c) {
  return __builtin_amdgcn_mfma_f32_16x16x32_bf16(
      __builtin_bit_cast(bf16x8, a), __builtin_bit_cast(bf16x8, b), c, 0, 0, 0);
}

#define GLOAD_LDS16(gaddr, laddr)                                              \
  __builtin_amdgcn_global_load_lds(                                            \
      (const __attribute__((address_space(1))) unsigned int*)(gaddr),          \
      (__attribute__((address_space(3))) unsigned int*)(laddr), 16, 0, 0)

// ---------------- bf16 MFMA GEMM:  C[M,N]f32 = A[M,K]bf16 @ W[N,K]bf16^T ----
// One global_load_lds issue (256 thr x 16B) covers 64 rows at BK=32 bf16.
// Block 256 = 4 waves in 2x2; per wave (BM/2)x(BN/2) output.
template <int BM, int BN>
__global__ __launch_bounds__(256) void gemm_bf16(
    const unsigned short* __restrict__ A,
    const unsigned short* __restrict__ W,
    const float* __restrict__ bias,
    float* __restrict__ C, int ldc, int Nout, int K)
{
  constexpr int BK  = 32;
  constexpr int FM  = BM / 32;
  constexpr int FN  = BN / 32;
  constexpr int NLA = BM / 64;     // load-issues to cover A tile
  constexpr int NLW = BN / 64;
  __shared__ unsigned short Alds[BM][BK];
  __shared__ unsigned short Wlds[BN][BK];

  const int tid  = threadIdx.x;
  const int w    = tid >> 6;
  const int lane = tid & 63;
  const int wr   = w >> 1, wc = w & 1;
  const int bm   = blockIdx.x * BM;
  const int bn   = blockIdx.y * BN;

  f32x4 acc[FM][FN];
#pragma unroll
  for (int m = 0; m < FM; ++m)
#pragma unroll
    for (int n = 0; n < FN; ++n) acc[m][n] = (f32x4){0.f, 0.f, 0.f, 0.f};

  const int srow = w * 16 + (lane >> 2);   // staging row within a 64-row band
  const int kq   = (lane & 3) * 8;         // lane's 16B k-offset (elements)

  const int frow = lane & 15;              // fragment row/col within 16
  const int kof  = (lane >> 4) * 8;        // fragment k-group (elements)

  for (int k0 = 0; k0 < K; k0 += BK) {
    __syncthreads();
#pragma unroll
    for (int j = 0; j < NLA; ++j)
      GLOAD_LDS16(A + (size_t)(bm + j * 64 + srow) * K + k0 + kq,
                  &Alds[j * 64 + w * 16][0]);
#pragma unroll
    for (int j = 0; j < NLW; ++j)
      GLOAD_LDS16(W + (size_t)(bn + j * 64 + srow) * K + k0 + kq,
                  &Wlds[j * 64 + w * 16][0]);
    __syncthreads();
    us8 af[FM], wf[FN];
#pragma unroll
    for (int m = 0; m < FM; ++m)
      af[m] = *(const us8*)&Alds[wr * (BM / 2) + m * 16 + frow][kof];
#pragma unroll
    for (int n = 0; n < FN; ++n)
      wf[n] = *(const us8*)&Wlds[wc * (BN / 2) + n * 16 + frow][kof];
#pragma unroll
    for (int m = 0; m < FM; ++m)
#pragma unroll
      for (int n = 0; n < FN; ++n)
        acc[m][n] = mfma_bf16(af[m], wf[n], acc[m][n]);
  }

  // epilogue: C/D layout col=lane&15, row=(lane>>4)*4+r  [m89-verified]
  const int rbase = (lane >> 4) * 4;
#pragma unroll
  for (int m = 0; m < FM; ++m) {
#pragma unroll
    for (int n = 0; n < FN; ++n) {
      const int col = bn + wc * (BN / 2) + n * 16 + (lane & 15);
      if (col < Nout) {
        const float bv = bias ? bias[col] : 0.f;
#pragma unroll
        for (int r = 0; r < 4; ++r) {
          const int row = bm + wr * (BM / 2) + m * 16 + rbase + r;
          C[(size_t)row * ldc + col] = acc[m][n][r] + bv;
        }
      }
    }
  }
}

// ---------------- fp32 GEMM (kept for dt_proj, K=64) ------------------------
template <int ACT>
__global__ __launch_bounds__(256) void gemm_nt(
    const float* __restrict__ A, int lda,
    const float* __restrict__ W, int ldw,
    const float* __restrict__ bias,
    float* __restrict__ C, int ldc,
    int N, int K)
{
  __shared__ float As[16][64];
  __shared__ float Ws[16][64];
  const int tid = threadIdx.x;
  const int bm = blockIdx.x * 64;
  const int bn = blockIdx.y * 64;
  const int tx = tid & 15;
  const int ty = tid >> 4;
  const int srow = tid >> 2;
  const int scg  = (tid & 3) * 4;

  float acc[4][4] = {};
  const float* Aptr = A + (size_t)(bm + srow) * lda + scg;
  const bool   wok  = (bn + srow) < N;
  const float* Wptr = W + (size_t)(bn + srow) * ldw + scg;

  for (int k0 = 0; k0 < K; k0 += 16) {
    float4 av = *(const float4*)(Aptr + k0);
    float4 wv = make_float4(0.f, 0.f, 0.f, 0.f);
    if (wok) wv = *(const float4*)(Wptr + k0);
    __syncthreads();
    As[scg + 0][srow] = av.x; As[scg + 1][srow] = av.y;
    As[scg + 2][srow] = av.z; As[scg + 3][srow] = av.w;
    Ws[scg + 0][srow] = wv.x; Ws[scg + 1][srow] = wv.y;
    Ws[scg + 2][srow] = wv.z; Ws[scg + 3][srow] = wv.w;
    __syncthreads();
#pragma unroll
    for (int k = 0; k < 16; ++k) {
      float4 a4 = *(const float4*)&As[k][ty * 4];
      float4 w4 = *(const float4*)&Ws[k][tx * 4];
      float a_[4] = {a4.x, a4.y, a4.z, a4.w};
      float w_[4] = {w4.x, w4.y, w4.z, w4.w};
#pragma unroll
      for (int i = 0; i < 4; ++i)
#pragma unroll
        for (int j = 0; j < 4; ++j)
          acc[i][j] += a_[i] * w_[j];
    }
  }

#pragma unroll
  for (int i = 0; i < 4; ++i) {
    const int row = bm + ty * 4 + i;
#pragma unroll
    for (int j = 0; j < 4; ++j) {
      const int col = bn + tx * 4 + j;
      if (col < N) {
        float v = acc[i][j];
        if (bias) v += bias[col];
        if (ACT == 1) v = (v > 20.f) ? v : log1pf(__expf(v));
        C[(size_t)row * ldc + col] = v;
      }
    }
  }
}

// ---------------- converts --------------------------------------------------
__global__ __launch_bounds__(256) void cvt_bf16_k(
    const float* __restrict__ in, unsigned short* __restrict__ out, int n4)
{
  const int i = blockIdx.x * 256 + threadIdx.x;
  if (i >= n4) return;
  float4 v = ((const float4*)in)[i];
  ushort4 o;
  o.x = f2b(v.x); o.y = f2b(v.y); o.z = f2b(v.z); o.w = f2b(v.w);
  ((ushort4*)out)[i] = o;
}

// x_proj_w (96,2048) -> bf16 padded to (128,2048), rows>=96 zero.
__global__ __launch_bounds__(256) void cvt_pad_xpw_k(
    const float* __restrict__ in, unsigned short* __restrict__ out)
{
  const int i = blockIdx.x * 256 + threadIdx.x;
  const int idx = i * 4;
  const int row = idx >> 11;
  ushort4 o = {0, 0, 0, 0};
  if (row < 96) {
    float4 v = *(const float4*)(in + idx);
    o.x = f2b(v.x); o.y = f2b(v.y); o.z = f2b(v.z); o.w = f2b(v.w);
  }
  *(ushort4*)(out + idx) = o;
}

// ---------------- conv + SiLU (emits fp32 + bf16) ---------------------------
__global__ __launch_bounds__(256) void conv_silu_k(
    const float* __restrict__ xz, const float* __restrict__ cw,
    const float* __restrict__ cb, float* __restrict__ xc,
    unsigned short* __restrict__ xcb)
{
  const int idx = blockIdx.x * 256 + threadIdx.x;
  const int row = idx >> 9;
  const int e   = (idx & 511) * 4;
  const int l   = row & 1023;
  const float* base = xz + (size_t)(row - l) * (2 * ED) + e;

  float4 acc = *(const float4*)(cb + e);
#pragma unroll
  for (int k = 0; k < 4; ++k) {
    const int ls = l - 3 + k;
    if (ls >= 0) {
      float4 v = *(const float4*)(base + (size_t)ls * (2 * ED));
      acc.x += cw[(size_t)(e + 0) * 4 + k] * v.x;
      acc.y += cw[(size_t)(e + 1) * 4 + k] * v.y;
      acc.z += cw[(size_t)(e + 2) * 4 + k] * v.z;
      acc.w += cw[(size_t)(e + 3) * 4 + k] * v.w;
    }
  }
  acc.x = silu_(acc.x); acc.y = silu_(acc.y);
  acc.z = silu_(acc.z); acc.w = silu_(acc.w);
  *(float4*)(xc + (size_t)row * ED + e) = acc;
  ushort4 o;
  o.x = f2b(acc.x); o.y = f2b(acc.y); o.z = f2b(acc.z); o.w = f2b(acc.w);
  *(ushort4*)(xcb + (size_t)row * ED + e) = o;
}

// ---------------- chunked selective scan ------------------------------------
__global__ __launch_bounds__(256) void scan_phase1(
    const float* __restrict__ dt, const float* __restrict__ xc,
    const float* __restrict__ dbc, const float* __restrict__ A_log,
    float* __restrict__ aprod_o, float* __restrict__ bfin_o)
{
  const int tid = blockIdx.x * 256 + threadIdx.x;
  const int e  = tid & (ED - 1);
  const int bc = tid >> 11;
  const int b  = bc >> 5;
  const int c  = bc & (CH - 1);

  float Aen[NST];
  {
    const float4* Ap = (const float4*)(A_log + (size_t)e * NST);
#pragma unroll
    for (int q = 0; q < 4; ++q) {
      float4 v = Ap[q];
      Aen[q * 4 + 0] = -__expf(v.x); Aen[q * 4 + 1] = -__expf(v.y);
      Aen[q * 4 + 2] = -__expf(v.z); Aen[q * 4 + 3] = -__expf(v.w);
    }
  }

  float h[NST], ap[NST];
#pragma unroll
  for (int n = 0; n < NST; ++n) { h[n] = 0.f; ap[n] = 1.f; }

  const size_t rowbase = (size_t)b * 1024 + (size_t)c * LC;
  for (int i = 0; i < LC; ++i) {
    const size_t rr = rowbase + i;
    const float dtv = dt[rr * ED + e];
    const float xcv = xc[rr * ED + e];
    const float dx  = dtv * xcv;
    float Bv[NST];
    {
      const float4* Bp = (const float4*)(dbc + rr * 96 + RLOW);
#pragma unroll
      for (int q = 0; q < 4; ++q) { float4 v = Bp[q];
        Bv[q*4+0]=v.x; Bv[q*4+1]=v.y; Bv[q*4+2]=v.z; Bv[q*4+3]=v.w; }
    }
#pragma unroll
    for (int n = 0; n < NST; ++n) {
      const float dA = __expf(dtv * Aen[n]);
      ap[n] *= dA;
      h[n] = dA * h[n] + dx * Bv[n];
    }
  }

  float* ao = aprod_o + ((size_t)((b * ED + e) * CH + c)) * NST;
  float* bo = bfin_o  + ((size_t)((b * ED + e) * CH + c)) * NST;
#pragma unroll
  for (int q = 0; q < 4; ++q) {
    ((float4*)ao)[q] = make_float4(ap[q*4+0], ap[q*4+1], ap[q*4+2], ap[q*4+3]);
    ((float4*)bo)[q] = make_float4(h[q*4+0],  h[q*4+1],  h[q*4+2],  h[q*4+3]);
  }
}

__global__ __launch_bounds__(256) void scan_phase2(
    const float* __restrict__ aprod, float* __restrict__ bfin)
{
  const int tid = blockIdx.x * 256 + threadIdx.x;
  const int n  = tid & (NST - 1);
  const int be = tid >> 4;
  const size_t base = (size_t)be * CH * NST + n;
  float hs = 0.f;
  for (int c = 0; c < CH; ++c) {
    const size_t idx = base + (size_t)c * NST;
    const float a  = aprod[idx];
    const float bf = bfin[idx];
    bfin[idx] = hs;
    hs = a * hs + bf;
  }
}

__global__ __launch_bounds__(256) void scan_phase3(
    const float* __restrict__ dt, const float* __restrict__ xc,
    const float* __restrict__ dbc, const float* __restrict__ A_log,
    const float* __restrict__ Dp, const float* __restrict__ xz,
    const float* __restrict__ hst, unsigned short* __restrict__ ygb)
{
  const int tid = blockIdx.x * 256 + threadIdx.x;
  const int e  = tid & (ED - 1);
  const int bc = tid >> 11;
  const int b  = bc >> 5;
  const int c  = bc & (CH - 1);

  float Aen[NST];
  {
    const float4* Ap = (const float4*)(A_log + (size_t)e * NST);
#pragma unroll
    for (int q = 0; q < 4; ++q) {
      float4 v = Ap[q];
      Aen[q * 4 + 0] = -__expf(v.x); Aen[q * 4 + 1] = -__expf(v.y);
      Aen[q * 4 + 2] = -__expf(v.z); Aen[q * 4 + 3] = -__expf(v.w);
    }
  }

  float h[NST];
  {
    const float4* Hp = (const float4*)(hst + ((size_t)((b * ED + e) * CH + c)) * NST);
#pragma unroll
    for (int q = 0; q < 4; ++q) { float4 v = Hp[q];
      h[q*4+0]=v.x; h[q*4+1]=v.y; h[q*4+2]=v.z; h[q*4+3]=v.w; }
  }

  const float De = Dp[e];
  const size_t rowbase = (size_t)b * 1024 + (size_t)c * LC;
  for (int i = 0; i < LC; ++i) {
    const size_t rr = rowbase + i;
    const float dtv = dt[rr * ED + e];
    const float xcv = xc[rr * ED + e];
    const float dx  = dtv * xcv;
    float Bv[NST], Cv[NST];
    {
      const float4* Bp = (const float4*)(dbc + rr * 96 + RLOW);
      const float4* Cp = (const float4*)(dbc + rr * 96 + RLOW + NST);
#pragma unroll
      for (int q = 0; q < 4; ++q) {
        float4 v = Bp[q];
        Bv[q*4+0]=v.x; Bv[q*4+1]=v.y; Bv[q*4+2]=v.z; Bv[q*4+3]=v.w;
        float4 w = Cp[q];
        Cv[q*4+0]=w.x; Cv[q*4+1]=w.y; Cv[q*4+2]=w.z; Cv[q*4+3]=w.w;
      }
    }
    float y = 0.f;
#pragma unroll
    for (int n = 0; n < NST; ++n) {
      const float dA = __expf(dtv * Aen[n]);
      h[n] = dA * h[n] + dx * Bv[n];
      y += Cv[n] * h[n];
    }
    y += De * xcv;
    const float zv = xz[rr * (2 * ED) + ED + e];
    ygb[rr * ED + e] = f2b(y * silu_(zv));
  }
}

extern "C" void kernel_launch(void* const* d_in, const int* in_sizes, int n_in,
                              void* d_out, int out_size, void* d_ws, size_t ws_size,
                              hipStream_t stream) {
  const float* x         = (const float*)d_in[0];
  const float* in_w      = (const float*)d_in[1];
  const float* in_b      = (const float*)d_in[2];
  const float* conv_w    = (const float*)d_in[3];
  const float* conv_b    = (const float*)d_in[4];
  const float* xproj_w   = (const float*)d_in[5];
  const float* dtproj_w  = (const float*)d_in[6];
  const float* dtproj_b  = (const float*)d_in[7];
  const float* A_log     = (const float*)d_in[8];
  const float* D_param   = (const float*)d_in[9];
  const float* outproj_w = (const float*)d_in[10];
  float* out = (float*)d_out;

  float* ws    = (float*)d_ws;
  float* xz    = ws;                  //  8,388,608 f
  float* xc    = xz    + 8388608;     //  4,194,304 f
  float* dbc   = xc    + 4194304;     //    196,608 f
  float* dtb   = dbc   + 196608;      //  4,194,304 f
  float* aprod = dtb   + 4194304;     //  2,097,152 f
  float* bfin  = aprod + 2097152;     //  2,097,152 f
  unsigned short* xb   = (unsigned short*)(bfin + 2097152); // 2,097,152 us
  unsigned short* iwb  = xb  + 2097152;                     // 4,194,304 us
  unsigned short* owb  = iwb + 4194304;                     // 2,097,152 us
  unsigned short* xpwb = owb + 2097152;                     //   262,144 us
  unsigned short* xcb  = xpwb + 262144;                     // 4,194,304 us
  unsigned short* ygb  = xcb + 4194304;                     // 4,194,304 us
  // total ~120 MB

  const dim3 blk(256);

  // 0) convert weights/activations to bf16
  cvt_bf16_k<<<dim3(2097152 / 4 / 256), blk, 0, stream>>>(x, xb, 2097152 / 4);
  cvt_bf16_k<<<dim3(4194304 / 4 / 256), blk, 0, stream>>>(in_w, iwb, 4194304 / 4);
  cvt_bf16_k<<<dim3(2097152 / 4 / 256), blk, 0, stream>>>(outproj_w, owb, 2097152 / 4);
  cvt_pad_xpw_k<<<dim3(262144 / 4 / 256), blk, 0, stream>>>(xproj_w, xpwb);

  // 1) xz = x @ in_proj_w^T + b        (2048 x 4096, K=1024) bf16 MFMA
  gemm_bf16<128, 128><<<dim3(BL / 128, 4096 / 128), blk, 0, stream>>>(
      xb, iwb, in_b, xz, 2 * ED, 2 * ED, DIM);

  // 2) xc = silu(conv(xz[:, :ED]) + cb), also bf16 copy
  conv_silu_k<<<dim3((BL * (ED / 4)) / 256), blk, 0, stream>>>(
      xz, conv_w, conv_b, xc, xcb);

  // 3) dbc = xc @ x_proj_w^T           (2048 x 96, K=2048) bf16 MFMA, padded N
  gemm_bf16<128, 128><<<dim3(BL / 128, 1), blk, 0, stream>>>(
      xcb, xpwb, nullptr, dbc, 96, 96, ED);

  // 4) dt = softplus(dbc[:, :64] @ dt_proj_w^T + dt_proj_b)  fp32
  gemm_nt<1><<<dim3(BL / 64, ED / 64), blk, 0, stream>>>(
      dbc, 96, dtproj_w, RLOW, dtproj_b, dtb, ED, ED, RLOW);

  // 5) chunked scan (fp32), phase3 emits bf16 gated y
  scan_phase1<<<dim3((2 * CH * ED) / 256), blk, 0, stream>>>(
      dtb, xc, dbc, A_log, aprod, bfin);
  scan_phase2<<<dim3((2 * ED * NST) / 256), blk, 0, stream>>>(aprod, bfin);
  scan_phase3<<<dim3((2 * CH * ED) / 256), blk, 0, stream>>>(
      dtb, xc, dbc, A_log, D_param, xz, bfin, ygb);

  // 6) out = yg @ out_proj_w^T         (2048 x 1024, K=2048) bf16 MFMA
  gemm_bf16<64, 128><<<dim3(BL / 64, 1024 / 128), blk, 0, stream>>>(
      ygb, owb, nullptr, out, DIM, DIM, ED);
}

// Round 7
// 253.290 us; speedup vs baseline: 4.4039x; 1.1320x over previous
//
#include <hip/hip_runtime.h>
#include <cstddef>

// ---------------------------------------------------------------------------
// Mamba block forward. B=2, L=1024, D=1024, ED=2048, N=16, R=64, K=4. BL=2048.
// Round 7: latency-optimized chunked scan (CH=64, reg-preload + LDS B/C stage,
// wave-parallel Kogge-Stone phase2), bf16 xz/xc end-to-end.
// ---------------------------------------------------------------------------

#define BL   2048
#define DIM  1024
#define ED   2048
#define NST  16
#define RLOW 64
#define CH   64
#define LC   16

typedef __attribute__((ext_vector_type(4))) float   f32x4;
typedef __attribute__((ext_vector_type(8))) __bf16  bf16x8;
typedef __attribute__((ext_vector_type(8))) unsigned short us8;

__device__ __forceinline__ float silu_(float x) {
  return x / (1.f + __expf(-x));
}

__device__ __forceinline__ unsigned short f2b(float x) {
  union { float f; unsigned int u; } v; v.f = x;
  unsigned int r = v.u + 0x7FFFu + ((v.u >> 16) & 1u);   // RNE
  return (unsigned short)(r >> 16);
}

__device__ __forceinline__ float b2f(unsigned short u) {
  union { unsigned int i; float f; } v; v.i = (unsigned int)u << 16; return v.f;
}

__device__ __forceinline__ f32x4 mfma_bf16(us8 a, us8 b, f32x4 c) {
  return __builtin_amdgcn_mfma_f32_16x16x32_bf16(
      __builtin_bit_cast(bf16x8, a), __builtin_bit_cast(bf16x8, b), c, 0, 0, 0);
}

#define GLOAD_LDS16(gaddr, laddr)                                              \
  __builtin_amdgcn_global_load_lds(                                            \
      (const __attribute__((address_space(1))) unsigned int*)(gaddr),          \
      (__attribute__((address_space(3))) unsigned int*)(laddr), 16, 0, 0)

// ---------------- bf16 MFMA GEMM ---------------------------------------------
// C[M,N] = A[M,K]bf16 @ W[N,K]bf16^T (+bias). OBF: bf16 output else f32.
template <int BM, int BN, bool OBF>
__global__ __launch_bounds__(256) void gemm_bf16(
    const unsigned short* __restrict__ A,
    const unsigned short* __restrict__ W,
    const float* __restrict__ bias,
    void* __restrict__ Cp, int ldc, int Nout, int K)
{
  constexpr int BK  = 32;
  constexpr int FM  = BM / 32;
  constexpr int FN  = BN / 32;
  constexpr int NLA = BM / 64;
  constexpr int NLW = BN / 64;
  __shared__ unsigned short Alds[BM][BK];
  __shared__ unsigned short Wlds[BN][BK];

  const int tid  = threadIdx.x;
  const int w    = tid >> 6;
  const int lane = tid & 63;
  const int wr   = w >> 1, wc = w & 1;
  const int bm   = blockIdx.x * BM;
  const int bn   = blockIdx.y * BN;

  f32x4 acc[FM][FN];
#pragma unroll
  for (int m = 0; m < FM; ++m)
#pragma unroll
    for (int n = 0; n < FN; ++n) acc[m][n] = (f32x4){0.f, 0.f, 0.f, 0.f};

  const int srow = w * 16 + (lane >> 2);
  const int kq   = (lane & 3) * 8;
  const int frow = lane & 15;
  const int kof  = (lane >> 4) * 8;

  for (int k0 = 0; k0 < K; k0 += BK) {
    __syncthreads();
#pragma unroll
    for (int j = 0; j < NLA; ++j)
      GLOAD_LDS16(A + (size_t)(bm + j * 64 + srow) * K + k0 + kq,
                  &Alds[j * 64 + w * 16][0]);
#pragma unroll
    for (int j = 0; j < NLW; ++j)
      GLOAD_LDS16(W + (size_t)(bn + j * 64 + srow) * K + k0 + kq,
                  &Wlds[j * 64 + w * 16][0]);
    __syncthreads();
    us8 af[FM], wf[FN];
#pragma unroll
    for (int m = 0; m < FM; ++m)
      af[m] = *(const us8*)&Alds[wr * (BM / 2) + m * 16 + frow][kof];
#pragma unroll
    for (int n = 0; n < FN; ++n)
      wf[n] = *(const us8*)&Wlds[wc * (BN / 2) + n * 16 + frow][kof];
#pragma unroll
    for (int m = 0; m < FM; ++m)
#pragma unroll
      for (int n = 0; n < FN; ++n)
        acc[m][n] = mfma_bf16(af[m], wf[n], acc[m][n]);
  }

  // C/D layout: col=lane&15, row=(lane>>4)*4+r  [m89-verified]
  const int rbase = (lane >> 4) * 4;
#pragma unroll
  for (int m = 0; m < FM; ++m) {
#pragma unroll
    for (int n = 0; n < FN; ++n) {
      const int col = bn + wc * (BN / 2) + n * 16 + (lane & 15);
      if (col < Nout) {
        const float bv = bias ? bias[col] : 0.f;
#pragma unroll
        for (int r = 0; r < 4; ++r) {
          const int row = bm + wr * (BM / 2) + m * 16 + rbase + r;
          const float v = acc[m][n][r] + bv;
          if (OBF) ((unsigned short*)Cp)[(size_t)row * ldc + col] = f2b(v);
          else     ((float*)Cp)[(size_t)row * ldc + col] = v;
        }
      }
    }
  }
}

// ---------------- fp32 GEMM (dt_proj, K=64) ---------------------------------
template <int ACT>
__global__ __launch_bounds__(256) void gemm_nt(
    const float* __restrict__ A, int lda,
    const float* __restrict__ W, int ldw,
    const float* __restrict__ bias,
    float* __restrict__ C, int ldc,
    int N, int K)
{
  __shared__ float As[16][64];
  __shared__ float Ws[16][64];
  const int tid = threadIdx.x;
  const int bm = blockIdx.x * 64;
  const int bn = blockIdx.y * 64;
  const int tx = tid & 15;
  const int ty = tid >> 4;
  const int srow = tid >> 2;
  const int scg  = (tid & 3) * 4;

  float acc[4][4] = {};
  const float* Aptr = A + (size_t)(bm + srow) * lda + scg;
  const bool   wok  = (bn + srow) < N;
  const float* Wptr = W + (size_t)(bn + srow) * ldw + scg;

  for (int k0 = 0; k0 < K; k0 += 16) {
    float4 av = *(const float4*)(Aptr + k0);
    float4 wv = make_float4(0.f, 0.f, 0.f, 0.f);
    if (wok) wv = *(const float4*)(Wptr + k0);
    __syncthreads();
    As[scg + 0][srow] = av.x; As[scg + 1][srow] = av.y;
    As[scg + 2][srow] = av.z; As[scg + 3][srow] = av.w;
    Ws[scg + 0][srow] = wv.x; Ws[scg + 1][srow] = wv.y;
    Ws[scg + 2][srow] = wv.z; Ws[scg + 3][srow] = wv.w;
    __syncthreads();
#pragma unroll
    for (int k = 0; k < 16; ++k) {
      float4 a4 = *(const float4*)&As[k][ty * 4];
      float4 w4 = *(const float4*)&Ws[k][tx * 4];
      float a_[4] = {a4.x, a4.y, a4.z, a4.w};
      float w_[4] = {w4.x, w4.y, w4.z, w4.w};
#pragma unroll
      for (int i = 0; i < 4; ++i)
#pragma unroll
        for (int j = 0; j < 4; ++j)
          acc[i][j] += a_[i] * w_[j];
    }
  }

#pragma unroll
  for (int i = 0; i < 4; ++i) {
    const int row = bm + ty * 4 + i;
#pragma unroll
    for (int j = 0; j < 4; ++j) {
      const int col = bn + tx * 4 + j;
      if (col < N) {
        float v = acc[i][j];
        if (bias) v += bias[col];
        if (ACT == 1) v = (v > 20.f) ? v : log1pf(__expf(v));
        C[(size_t)row * ldc + col] = v;
      }
    }
  }
}

// ---------------- converts --------------------------------------------------
__global__ __launch_bounds__(256) void cvt_bf16_k(
    const float* __restrict__ in, unsigned short* __restrict__ out, int n4)
{
  const int i = blockIdx.x * 256 + threadIdx.x;
  if (i >= n4) return;
  float4 v = ((const float4*)in)[i];
  ushort4 o;
  o.x = f2b(v.x); o.y = f2b(v.y); o.z = f2b(v.z); o.w = f2b(v.w);
  ((ushort4*)out)[i] = o;
}

__global__ __launch_bounds__(256) void cvt_pad_xpw_k(
    const float* __restrict__ in, unsigned short* __restrict__ out)
{
  const int i = blockIdx.x * 256 + threadIdx.x;
  const int idx = i * 4;
  const int row = idx >> 11;
  ushort4 o = {0, 0, 0, 0};
  if (row < 96) {
    float4 v = *(const float4*)(in + idx);
    o.x = f2b(v.x); o.y = f2b(v.y); o.z = f2b(v.z); o.w = f2b(v.w);
  }
  *(ushort4*)(out + idx) = o;
}

// ---------------- conv + SiLU (bf16 in, bf16 out) ---------------------------
__global__ __launch_bounds__(256) void conv_silu_k(
    const unsigned short* __restrict__ xzb, const float* __restrict__ cw,
    const float* __restrict__ cb, unsigned short* __restrict__ xcb)
{
  const int idx = blockIdx.x * 256 + threadIdx.x;   // BL*ED/4 threads
  const int row = idx >> 9;
  const int e   = (idx & 511) * 4;
  const int l   = row & 1023;
  const unsigned short* base = xzb + (size_t)(row - l) * (2 * ED) + e;

  float4 cbv = *(const float4*)(cb + e);
  float a0 = cbv.x, a1 = cbv.y, a2 = cbv.z, a3 = cbv.w;
#pragma unroll
  for (int k = 0; k < 4; ++k) {
    const int ls = l - 3 + k;
    if (ls >= 0) {
      ushort4 u = *(const ushort4*)(base + (size_t)ls * (2 * ED));
      a0 += cw[(size_t)(e + 0) * 4 + k] * b2f(u.x);
      a1 += cw[(size_t)(e + 1) * 4 + k] * b2f(u.y);
      a2 += cw[(size_t)(e + 2) * 4 + k] * b2f(u.z);
      a3 += cw[(size_t)(e + 3) * 4 + k] * b2f(u.w);
    }
  }
  ushort4 o;
  o.x = f2b(silu_(a0)); o.y = f2b(silu_(a1));
  o.z = f2b(silu_(a2)); o.w = f2b(silu_(a3));
  *(ushort4*)(xcb + (size_t)row * ED + e) = o;
}

// ---------------- chunked selective scan ------------------------------------
// Summary layout: S[be][c][n], be = b*ED + e; idx = (be*CH + c)*NST + n.
// Phase 1: thread per (b,c,e); block shares (b,c) -> dbc B rows staged in LDS.
__global__ __launch_bounds__(256, 4) void scan_phase1(
    const float* __restrict__ dt, const unsigned short* __restrict__ xcb,
    const float* __restrict__ dbc, const float* __restrict__ A_log,
    float* __restrict__ aprod_o, float* __restrict__ bfin_o)
{
  const int g  = blockIdx.x * 256 + threadIdx.x;   // B*CH*ED = 262144
  const int e  = g & (ED - 1);
  const int bc = g >> 11;
  const int b  = bc >> 6;
  const int c  = bc & (CH - 1);
  const size_t rowbase = (size_t)b * 1024 + (size_t)c * LC;

  __shared__ float4 sB[LC][4];
  if (threadIdx.x < LC * 4) {
    const int row = threadIdx.x >> 2, q = threadIdx.x & 3;
    sB[row][q] = ((const float4*)(dbc + (rowbase + row) * 96 + RLOW))[q];
  }
  __syncthreads();

  float Aen[NST];
  {
    const float4* Ap = (const float4*)(A_log + (size_t)e * NST);
#pragma unroll
    for (int q = 0; q < 4; ++q) {
      float4 v = Ap[q];
      Aen[q*4+0] = -__expf(v.x); Aen[q*4+1] = -__expf(v.y);
      Aen[q*4+2] = -__expf(v.z); Aen[q*4+3] = -__expf(v.w);
    }
  }

  float dtv[LC], dxv[LC];
#pragma unroll
  for (int i = 0; i < LC; ++i) dtv[i] = dt[(rowbase + i) * ED + e];
#pragma unroll
  for (int i = 0; i < LC; ++i)
    dxv[i] = dtv[i] * b2f(xcb[(rowbase + i) * ED + e]);

  float h[NST], ap[NST];
#pragma unroll
  for (int n = 0; n < NST; ++n) { h[n] = 0.f; ap[n] = 1.f; }

  for (int i = 0; i < LC; ++i) {
    float Bv[NST];
#pragma unroll
    for (int q = 0; q < 4; ++q) {
      float4 v = sB[i][q];
      Bv[q*4+0]=v.x; Bv[q*4+1]=v.y; Bv[q*4+2]=v.z; Bv[q*4+3]=v.w;
    }
#pragma unroll
    for (int n = 0; n < NST; ++n) {
      const float dA = __expf(dtv[i] * Aen[n]);
      ap[n] *= dA;
      h[n] = fmaf(dA, h[n], dxv[i] * Bv[n]);
    }
  }

  const size_t obase = ((size_t)(b * ED + e) * CH + c) * NST;
  float4* ao = (float4*)(aprod_o + obase);
  float4* bo = (float4*)(bfin_o + obase);
#pragma unroll
  for (int q = 0; q < 4; ++q) {
    ao[q] = make_float4(ap[q*4+0], ap[q*4+1], ap[q*4+2], ap[q*4+3]);
    bo[q] = make_float4(h[q*4+0],  h[q*4+1],  h[q*4+2],  h[q*4+3]);
  }
}

// Phase 2: one wave per be; lane = chunk. 16 register-wise Kogge-Stone scans.
// Overwrites bfin with per-chunk STARTING states.
__global__ __launch_bounds__(256) void scan_phase2(
    const float* __restrict__ aprod, float* __restrict__ bfin)
{
  const int be   = blockIdx.x * 4 + (threadIdx.x >> 6);  // 0..4095
  const int lane = threadIdx.x & 63;
  const size_t base = (size_t)be * CH * NST;             // 1024 floats

  float Aa[NST], Bb[NST];
  {
    const float4* ap4 = (const float4*)(aprod + base);
    const float4* bp4 = (const float4*)(bfin + base);
#pragma unroll
    for (int q = 0; q < 4; ++q) {
      float4 v = ap4[lane * 4 + q];
      Aa[q*4+0]=v.x; Aa[q*4+1]=v.y; Aa[q*4+2]=v.z; Aa[q*4+3]=v.w;
      float4 w = bp4[lane * 4 + q];
      Bb[q*4+0]=w.x; Bb[q*4+1]=w.y; Bb[q*4+2]=w.z; Bb[q*4+3]=w.w;
    }
  }

#pragma unroll
  for (int d = 1; d < 64; d <<= 1) {
#pragma unroll
    for (int r = 0; r < NST; ++r) {
      const float aP = __shfl_up(Aa[r], d);
      const float bP = __shfl_up(Bb[r], d);
      if (lane >= d) {
        Bb[r] = fmaf(Aa[r], bP, Bb[r]);
        Aa[r] *= aP;
      }
    }
  }

  // exclusive: start state of chunk `lane` = inclusive B of lane-1 (0 for lane 0)
#pragma unroll
  for (int r = 0; r < NST; ++r) {
    const float hs = __shfl_up(Bb[r], 1);
    Bb[r] = (lane == 0) ? 0.f : hs;
  }

  float4* ob4 = (float4*)(bfin + base);
#pragma unroll
  for (int q = 0; q < 4; ++q)
    ob4[lane * 4 + q] = make_float4(Bb[q*4+0], Bb[q*4+1], Bb[q*4+2], Bb[q*4+3]);
}

// Phase 3: recompute chunk from start state; fused D*xc + z-gate; bf16 out.
__global__ __launch_bounds__(256, 4) void scan_phase3(
    const float* __restrict__ dt, const unsigned short* __restrict__ xcb,
    const float* __restrict__ dbc, const float* __restrict__ A_log,
    const float* __restrict__ Dp, const unsigned short* __restrict__ xzb,
    const float* __restrict__ hst, unsigned short* __restrict__ ygb)
{
  const int g  = blockIdx.x * 256 + threadIdx.x;
  const int e  = g & (ED - 1);
  const int bc = g >> 11;
  const int b  = bc >> 6;
  const int c  = bc & (CH - 1);
  const size_t rowbase = (size_t)b * 1024 + (size_t)c * LC;

  __shared__ float4 sBC[LC][8];
  if (threadIdx.x < LC * 8) {
    const int row = threadIdx.x >> 3, q = threadIdx.x & 7;
    sBC[row][q] = ((const float4*)(dbc + (rowbase + row) * 96 + RLOW))[q];
  }
  __syncthreads();

  float Aen[NST];
  {
    const float4* Ap = (const float4*)(A_log + (size_t)e * NST);
#pragma unroll
    for (int q = 0; q < 4; ++q) {
      float4 v = Ap[q];
      Aen[q*4+0] = -__expf(v.x); Aen[q*4+1] = -__expf(v.y);
      Aen[q*4+2] = -__expf(v.z); Aen[q*4+3] = -__expf(v.w);
    }
  }

  float dtv[LC], xcv[LC];
#pragma unroll
  for (int i = 0; i < LC; ++i) dtv[i] = dt[(rowbase + i) * ED + e];
#pragma unroll
  for (int i = 0; i < LC; ++i) xcv[i] = b2f(xcb[(rowbase + i) * ED + e]);

  float h[NST];
  {
    const float4* Hp = (const float4*)(hst + ((size_t)(b * ED + e) * CH + c) * NST);
#pragma unroll
    for (int q = 0; q < 4; ++q) {
      float4 v = Hp[q];
      h[q*4+0]=v.x; h[q*4+1]=v.y; h[q*4+2]=v.z; h[q*4+3]=v.w;
    }
  }

  const float De = Dp[e];
  for (int i = 0; i < LC; ++i) {
    const size_t rr = rowbase + i;
    float Bv[NST], Cv[NST];
#pragma unroll
    for (int q = 0; q < 4; ++q) {
      float4 v = sBC[i][q];
      Bv[q*4+0]=v.x; Bv[q*4+1]=v.y; Bv[q*4+2]=v.z; Bv[q*4+3]=v.w;
      float4 w = sBC[i][q + 4];
      Cv[q*4+0]=w.x; Cv[q*4+1]=w.y; Cv[q*4+2]=w.z; Cv[q*4+3]=w.w;
    }
    const float dx = dtv[i] * xcv[i];
    float y = 0.f;
#pragma unroll
    for (int n = 0; n < NST; ++n) {
      const float dA = __expf(dtv[i] * Aen[n]);
      h[n] = fmaf(dA, h[n], dx * Bv[n]);
      y = fmaf(Cv[n], h[n], y);
    }
    y = fmaf(De, xcv[i], y);
    const float zf = b2f(xzb[rr * (2 * ED) + ED + e]);
    ygb[rr * ED + e] = f2b(y * silu_(zf));
  }
}

extern "C" void kernel_launch(void* const* d_in, const int* in_sizes, int n_in,
                              void* d_out, int out_size, void* d_ws, size_t ws_size,
                              hipStream_t stream) {
  const float* x         = (const float*)d_in[0];
  const float* in_w      = (const float*)d_in[1];
  const float* in_b      = (const float*)d_in[2];
  const float* conv_w    = (const float*)d_in[3];
  const float* conv_b    = (const float*)d_in[4];
  const float* xproj_w   = (const float*)d_in[5];
  const float* dtproj_w  = (const float*)d_in[6];
  const float* dtproj_b  = (const float*)d_in[7];
  const float* A_log     = (const float*)d_in[8];
  const float* D_param   = (const float*)d_in[9];
  const float* outproj_w = (const float*)d_in[10];
  float* out = (float*)d_out;

  float* ws    = (float*)d_ws;
  float* dbc   = ws;                  //    196,608 f ( 0.75 MB)
  float* dtb   = dbc   + 196608;      //  4,194,304 f (16 MB)
  float* aprod = dtb   + 4194304;     //  4,194,304 f (16 MB)  B*ED*CH*NST
  float* bfin  = aprod + 4194304;     //  4,194,304 f (16 MB)
  unsigned short* xzb  = (unsigned short*)(bfin + 4194304); // 8,388,608 us (16 MB)
  unsigned short* xb   = xzb  + 8388608;                    // 2,097,152 us ( 4 MB)
  unsigned short* iwb  = xb   + 2097152;                    // 4,194,304 us ( 8 MB)
  unsigned short* owb  = iwb  + 4194304;                    // 2,097,152 us ( 4 MB)
  unsigned short* xpwb = owb  + 2097152;                    //   262,144 us ( 0.5 MB)
  unsigned short* xcb  = xpwb + 262144;                     // 4,194,304 us ( 8 MB)
  unsigned short* ygb  = xcb  + 4194304;                    // 4,194,304 us ( 8 MB)
  // total ~97.25 MB

  const dim3 blk(256);

  // 0) convert inputs/weights to bf16
  cvt_bf16_k<<<dim3(2097152 / 4 / 256), blk, 0, stream>>>(x, xb, 2097152 / 4);
  cvt_bf16_k<<<dim3(4194304 / 4 / 256), blk, 0, stream>>>(in_w, iwb, 4194304 / 4);
  cvt_bf16_k<<<dim3(2097152 / 4 / 256), blk, 0, stream>>>(outproj_w, owb, 2097152 / 4);
  cvt_pad_xpw_k<<<dim3(262144 / 4 / 256), blk, 0, stream>>>(xproj_w, xpwb);

  // 1) xz = x @ in_proj_w^T + b  -> bf16 (2048 x 4096, K=1024)
  gemm_bf16<128, 128, true><<<dim3(BL / 128, 4096 / 128), blk, 0, stream>>>(
      xb, iwb, in_b, xzb, 2 * ED, 2 * ED, DIM);

  // 2) xc = silu(conv(xz[:, :ED]) + cb) -> bf16
  conv_silu_k<<<dim3((BL * (ED / 4)) / 256), blk, 0, stream>>>(
      xzb, conv_w, conv_b, xcb);

  // 3) dbc = xc @ x_proj_w^T -> f32 (2048 x 96, K=2048)
  gemm_bf16<128, 128, false><<<dim3(BL / 128, 1), blk, 0, stream>>>(
      xcb, xpwb, nullptr, dbc, 96, 96, ED);

  // 4) dt = softplus(dbc[:, :64] @ dt_proj_w^T + dt_proj_b)  f32
  gemm_nt<1><<<dim3(BL / 64, ED / 64), blk, 0, stream>>>(
      dbc, 96, dtproj_w, RLOW, dtproj_b, dtb, ED, ED, RLOW);

  // 5) chunked scan
  scan_phase1<<<dim3((2 * CH * ED) / 256), blk, 0, stream>>>(
      dtb, xcb, dbc, A_log, aprod, bfin);
  scan_phase2<<<dim3((2 * ED) / 4), blk, 0, stream>>>(aprod, bfin);
  scan_phase3<<<dim3((2 * CH * ED) / 256), blk, 0, stream>>>(
      dtb, xcb, dbc, A_log, D_param, xzb, bfin, ygb);

  // 6) out = yg @ out_proj_w^T -> f32 (2048 x 1024, K=2048)
  gemm_bf16<64, 128, false><<<dim3(BL / 64, 1024 / 128), blk, 0, stream>>>(
      ygb, owb, nullptr, out, DIM, DIM, ED);
}

// Round 8
// 232.360 us; speedup vs baseline: 4.8006x; 1.0901x over previous
//
#include <hip/hip_runtime.h>
#include <cstddef>

// ---------------------------------------------------------------------------
// Mamba block forward. B=2, L=1024, D=1024, ED=2048, N=16, R=64, K=4. BL=2048.
// Round 8: split-K x_proj (16 blocks -> 256), conflict-free LDS interleave,
// out_proj 64x64 tile.
// ---------------------------------------------------------------------------

#define BL   2048
#define DIM  1024
#define ED   2048
#define NST  16
#define RLOW 64
#define CH   64
#define LC   16
#define SK   16        // K-splits for x_proj
#define DBCN 196608    // BL*96

typedef __attribute__((ext_vector_type(4))) float   f32x4;
typedef __attribute__((ext_vector_type(8))) __bf16  bf16x8;
typedef __attribute__((ext_vector_type(8))) unsigned short us8;

__device__ __forceinline__ float silu_(float x) {
  return x / (1.f + __expf(-x));
}

__device__ __forceinline__ unsigned short f2b(float x) {
  union { float f; unsigned int u; } v; v.f = x;
  unsigned int r = v.u + 0x7FFFu + ((v.u >> 16) & 1u);   // RNE
  return (unsigned short)(r >> 16);
}

__device__ __forceinline__ float b2f(unsigned short u) {
  union { unsigned int i; float f; } v; v.i = (unsigned int)u << 16; return v.f;
}

__device__ __forceinline__ f32x4 mfma_bf16(us8 a, us8 b, f32x4 c) {
  return __builtin_amdgcn_mfma_f32_16x16x32_bf16(
      __builtin_bit_cast(bf16x8, a), __builtin_bit_cast(bf16x8, b), c, 0, 0, 0);
}

#define GLOAD_LDS16(gaddr, laddr)                                              \
  __builtin_amdgcn_global_load_lds(                                            \
      (const __attribute__((address_space(1))) unsigned int*)(gaddr),          \
      (__attribute__((address_space(3))) unsigned int*)(laddr), 16, 0, 0)

// ---------------- bf16 MFMA GEMM ---------------------------------------------
// C[M,N] = A[M,K]bf16 @ W[N,K]bf16^T (+bias). OBF: bf16 out else f32.
// lda = row stride of A and W; Kloop = K extent this block walks;
// blockIdx.z = K-split index (A/W advanced by z*Kloop; C by z*sstride floats).
// LDS layout: per 16-row group, chunk (row,kg) at position kg*16+row, so a
// wave's fragment read is base + lane*16B (sequential, conflict-free). The
// stager fetches global chunk (row=lane&15, kg=lane>>4) to make that hold.
template <int BM, int BN, bool OBF>
__global__ __launch_bounds__(256) void gemm_bf16(
    const unsigned short* __restrict__ A,
    const unsigned short* __restrict__ W,
    const float* __restrict__ bias,
    void* __restrict__ Cp, int ldc, int Nout, int Kloop, int lda, int sstride)
{
  constexpr int BK  = 32;
  constexpr int FM  = BM / 32;
  constexpr int FN  = BN / 32;
  constexpr int NLA = BM / 64;
  constexpr int NLW = BN / 64;
  __shared__ unsigned short Alds[BM][BK];
  __shared__ unsigned short Wlds[BN][BK];

  const int tid  = threadIdx.x;
  const int w    = tid >> 6;
  const int lane = tid & 63;
  const int wr   = w >> 1, wc = w & 1;
  const int bm   = blockIdx.x * BM;
  const int bn   = blockIdx.y * BN;
  const int kb   = blockIdx.z * Kloop;

  f32x4 acc[FM][FN];
#pragma unroll
  for (int m = 0; m < FM; ++m)
#pragma unroll
    for (int n = 0; n < FN; ++n) acc[m][n] = (f32x4){0.f, 0.f, 0.f, 0.f};

  const int srow = w * 16 + (lane & 15);   // staged global row within band
  const int kq   = (lane >> 4) * 8;        // staged k-chunk (elements)

  for (int k0 = 0; k0 < Kloop; k0 += BK) {
    __syncthreads();
#pragma unroll
    for (int j = 0; j < NLA; ++j)
      GLOAD_LDS16(A + (size_t)(bm + j * 64 + srow) * lda + kb + k0 + kq,
                  &Alds[j * 64 + w * 16][0]);
#pragma unroll
    for (int j = 0; j < NLW; ++j)
      GLOAD_LDS16(W + (size_t)(bn + j * 64 + srow) * lda + kb + k0 + kq,
                  &Wlds[j * 64 + w * 16][0]);
    __syncthreads();
    us8 af[FM], wf[FN];
#pragma unroll
    for (int m = 0; m < FM; ++m)
      af[m] = *(const us8*)(&Alds[0][0] + (wr * (BM / 2) + m * 16) * BK + lane * 8);
#pragma unroll
    for (int n = 0; n < FN; ++n)
      wf[n] = *(const us8*)(&Wlds[0][0] + (wc * (BN / 2) + n * 16) * BK + lane * 8);
#pragma unroll
    for (int m = 0; m < FM; ++m)
#pragma unroll
      for (int n = 0; n < FN; ++n)
        acc[m][n] = mfma_bf16(af[m], wf[n], acc[m][n]);
  }

  // C/D layout: col=lane&15, row=(lane>>4)*4+r  [m89-verified]
  const int rbase = (lane >> 4) * 4;
  float* Cf = (float*)Cp + (size_t)blockIdx.z * sstride;
#pragma unroll
  for (int m = 0; m < FM; ++m) {
#pragma unroll
    for (int n = 0; n < FN; ++n) {
      const int col = bn + wc * (BN / 2) + n * 16 + (lane & 15);
      if (col < Nout) {
        const float bv = bias ? bias[col] : 0.f;
#pragma unroll
        for (int r = 0; r < 4; ++r) {
          const int row = bm + wr * (BM / 2) + m * 16 + rbase + r;
          const float v = acc[m][n][r] + bv;
          if (OBF) ((unsigned short*)Cp)[(size_t)row * ldc + col] = f2b(v);
          else     Cf[(size_t)row * ldc + col] = v;
        }
      }
    }
  }
}

// dbc = sum over SK split-K partials
__global__ __launch_bounds__(256) void reduce_dbc_k(
    const float* __restrict__ par, float* __restrict__ dbc)
{
  const int i = blockIdx.x * 256 + threadIdx.x;   // DBCN/4 threads
  float4 s = ((const float4*)par)[i];
#pragma unroll
  for (int sk = 1; sk < SK; ++sk) {
    float4 v = ((const float4*)(par + (size_t)sk * DBCN))[i];
    s.x += v.x; s.y += v.y; s.z += v.z; s.w += v.w;
  }
  ((float4*)dbc)[i] = s;
}

// ---------------- fp32 GEMM (dt_proj, K=64) ---------------------------------
template <int ACT>
__global__ __launch_bounds__(256) void gemm_nt(
    const float* __restrict__ A, int lda,
    const float* __restrict__ W, int ldw,
    const float* __restrict__ bias,
    float* __restrict__ C, int ldc,
    int N, int K)
{
  __shared__ float As[16][64];
  __shared__ float Ws[16][64];
  const int tid = threadIdx.x;
  const int bm = blockIdx.x * 64;
  const int bn = blockIdx.y * 64;
  const int tx = tid & 15;
  const int ty = tid >> 4;
  const int srow = tid >> 2;
  const int scg  = (tid & 3) * 4;

  float acc[4][4] = {};
  const float* Aptr = A + (size_t)(bm + srow) * lda + scg;
  const bool   wok  = (bn + srow) < N;
  const float* Wptr = W + (size_t)(bn + srow) * ldw + scg;

  for (int k0 = 0; k0 < K; k0 += 16) {
    float4 av = *(const float4*)(Aptr + k0);
    float4 wv = make_float4(0.f, 0.f, 0.f, 0.f);
    if (wok) wv = *(const float4*)(Wptr + k0);
    __syncthreads();
    As[scg + 0][srow] = av.x; As[scg + 1][srow] = av.y;
    As[scg + 2][srow] = av.z; As[scg + 3][srow] = av.w;
    Ws[scg + 0][srow] = wv.x; Ws[scg + 1][srow] = wv.y;
    Ws[scg + 2][srow] = wv.z; Ws[scg + 3][srow] = wv.w;
    __syncthreads();
#pragma unroll
    for (int k = 0; k < 16; ++k) {
      float4 a4 = *(const float4*)&As[k][ty * 4];
      float4 w4 = *(const float4*)&Ws[k][tx * 4];
      float a_[4] = {a4.x, a4.y, a4.z, a4.w};
      float w_[4] = {w4.x, w4.y, w4.z, w4.w};
#pragma unroll
      for (int i = 0; i < 4; ++i)
#pragma unroll
        for (int j = 0; j < 4; ++j)
          acc[i][j] += a_[i] * w_[j];
    }
  }

#pragma unroll
  for (int i = 0; i < 4; ++i) {
    const int row = bm + ty * 4 + i;
#pragma unroll
    for (int j = 0; j < 4; ++j) {
      const int col = bn + tx * 4 + j;
      if (col < N) {
        float v = acc[i][j];
        if (bias) v += bias[col];
        if (ACT == 1) v = (v > 20.f) ? v : log1pf(__expf(v));
        C[(size_t)row * ldc + col] = v;
      }
    }
  }
}

// ---------------- converts --------------------------------------------------
__global__ __launch_bounds__(256) void cvt_bf16_k(
    const float* __restrict__ in, unsigned short* __restrict__ out, int n4)
{
  const int i = blockIdx.x * 256 + threadIdx.x;
  if (i >= n4) return;
  float4 v = ((const float4*)in)[i];
  ushort4 o;
  o.x = f2b(v.x); o.y = f2b(v.y); o.z = f2b(v.z); o.w = f2b(v.w);
  ((ushort4*)out)[i] = o;
}

__global__ __launch_bounds__(256) void cvt_pad_xpw_k(
    const float* __restrict__ in, unsigned short* __restrict__ out)
{
  const int i = blockIdx.x * 256 + threadIdx.x;
  const int idx = i * 4;
  const int row = idx >> 11;
  ushort4 o = {0, 0, 0, 0};
  if (row < 96) {
    float4 v = *(const float4*)(in + idx);
    o.x = f2b(v.x); o.y = f2b(v.y); o.z = f2b(v.z); o.w = f2b(v.w);
  }
  *(ushort4*)(out + idx) = o;
}

// ---------------- conv + SiLU (bf16 in, bf16 out) ---------------------------
__global__ __launch_bounds__(256) void conv_silu_k(
    const unsigned short* __restrict__ xzb, const float* __restrict__ cw,
    const float* __restrict__ cb, unsigned short* __restrict__ xcb)
{
  const int idx = blockIdx.x * 256 + threadIdx.x;
  const int row = idx >> 9;
  const int e   = (idx & 511) * 4;
  const int l   = row & 1023;
  const unsigned short* base = xzb + (size_t)(row - l) * (2 * ED) + e;

  float4 cbv = *(const float4*)(cb + e);
  float a0 = cbv.x, a1 = cbv.y, a2 = cbv.z, a3 = cbv.w;
#pragma unroll
  for (int k = 0; k < 4; ++k) {
    const int ls = l - 3 + k;
    if (ls >= 0) {
      ushort4 u = *(const ushort4*)(base + (size_t)ls * (2 * ED));
      a0 += cw[(size_t)(e + 0) * 4 + k] * b2f(u.x);
      a1 += cw[(size_t)(e + 1) * 4 + k] * b2f(u.y);
      a2 += cw[(size_t)(e + 2) * 4 + k] * b2f(u.z);
      a3 += cw[(size_t)(e + 3) * 4 + k] * b2f(u.w);
    }
  }
  ushort4 o;
  o.x = f2b(silu_(a0)); o.y = f2b(silu_(a1));
  o.z = f2b(silu_(a2)); o.w = f2b(silu_(a3));
  *(ushort4*)(xcb + (size_t)row * ED + e) = o;
}

// ---------------- chunked selective scan ------------------------------------
__global__ __launch_bounds__(256, 4) void scan_phase1(
    const float* __restrict__ dt, const unsigned short* __restrict__ xcb,
    const float* __restrict__ dbc, const float* __restrict__ A_log,
    float* __restrict__ aprod_o, float* __restrict__ bfin_o)
{
  const int g  = blockIdx.x * 256 + threadIdx.x;
  const int e  = g & (ED - 1);
  const int bc = g >> 11;
  const int b  = bc >> 6;
  const int c  = bc & (CH - 1);
  const size_t rowbase = (size_t)b * 1024 + (size_t)c * LC;

  __shared__ float4 sB[LC][4];
  if (threadIdx.x < LC * 4) {
    const int row = threadIdx.x >> 2, q = threadIdx.x & 3;
    sB[row][q] = ((const float4*)(dbc + (rowbase + row) * 96 + RLOW))[q];
  }
  __syncthreads();

  float Aen[NST];
  {
    const float4* Ap = (const float4*)(A_log + (size_t)e * NST);
#pragma unroll
    for (int q = 0; q < 4; ++q) {
      float4 v = Ap[q];
      Aen[q*4+0] = -__expf(v.x); Aen[q*4+1] = -__expf(v.y);
      Aen[q*4+2] = -__expf(v.z); Aen[q*4+3] = -__expf(v.w);
    }
  }

  float dtv[LC], dxv[LC];
#pragma unroll
  for (int i = 0; i < LC; ++i) dtv[i] = dt[(rowbase + i) * ED + e];
#pragma unroll
  for (int i = 0; i < LC; ++i)
    dxv[i] = dtv[i] * b2f(xcb[(rowbase + i) * ED + e]);

  float h[NST], ap[NST];
#pragma unroll
  for (int n = 0; n < NST; ++n) { h[n] = 0.f; ap[n] = 1.f; }

  for (int i = 0; i < LC; ++i) {
    float Bv[NST];
#pragma unroll
    for (int q = 0; q < 4; ++q) {
      float4 v = sB[i][q];
      Bv[q*4+0]=v.x; Bv[q*4+1]=v.y; Bv[q*4+2]=v.z; Bv[q*4+3]=v.w;
    }
#pragma unroll
    for (int n = 0; n < NST; ++n) {
      const float dA = __expf(dtv[i] * Aen[n]);
      ap[n] *= dA;
      h[n] = fmaf(dA, h[n], dxv[i] * Bv[n]);
    }
  }

  const size_t obase = ((size_t)(b * ED + e) * CH + c) * NST;
  float4* ao = (float4*)(aprod_o + obase);
  float4* bo = (float4*)(bfin_o + obase);
#pragma unroll
  for (int q = 0; q < 4; ++q) {
    ao[q] = make_float4(ap[q*4+0], ap[q*4+1], ap[q*4+2], ap[q*4+3]);
    bo[q] = make_float4(h[q*4+0],  h[q*4+1],  h[q*4+2],  h[q*4+3]);
  }
}

__global__ __launch_bounds__(256) void scan_phase2(
    const float* __restrict__ aprod, float* __restrict__ bfin)
{
  const int be   = blockIdx.x * 4 + (threadIdx.x >> 6);
  const int lane = threadIdx.x & 63;
  const size_t base = (size_t)be * CH * NST;

  float Aa[NST], Bb[NST];
  {
    const float4* ap4 = (const float4*)(aprod + base);
    const float4* bp4 = (const float4*)(bfin + base);
#pragma unroll
    for (int q = 0; q < 4; ++q) {
      float4 v = ap4[lane * 4 + q];
      Aa[q*4+0]=v.x; Aa[q*4+1]=v.y; Aa[q*4+2]=v.z; Aa[q*4+3]=v.w;
      float4 w = bp4[lane * 4 + q];
      Bb[q*4+0]=w.x; Bb[q*4+1]=w.y; Bb[q*4+2]=w.z; Bb[q*4+3]=w.w;
    }
  }

#pragma unroll
  for (int d = 1; d < 64; d <<= 1) {
#pragma unroll
    for (int r = 0; r < NST; ++r) {
      const float aP = __shfl_up(Aa[r], d);
      const float bP = __shfl_up(Bb[r], d);
      if (lane >= d) {
        Bb[r] = fmaf(Aa[r], bP, Bb[r]);
        Aa[r] *= aP;
      }
    }
  }

#pragma unroll
  for (int r = 0; r < NST; ++r) {
    const float hs = __shfl_up(Bb[r], 1);
    Bb[r] = (lane == 0) ? 0.f : hs;
  }

  float4* ob4 = (float4*)(bfin + base);
#pragma unroll
  for (int q = 0; q < 4; ++q)
    ob4[lane * 4 + q] = make_float4(Bb[q*4+0], Bb[q*4+1], Bb[q*4+2], Bb[q*4+3]);
}

__global__ __launch_bounds__(256, 4) void scan_phase3(
    const float* __restrict__ dt, const unsigned short* __restrict__ xcb,
    const float* __restrict__ dbc, const float* __restrict__ A_log,
    const float* __restrict__ Dp, const unsigned short* __restrict__ xzb,
    const float* __restrict__ hst, unsigned short* __restrict__ ygb)
{
  const int g  = blockIdx.x * 256 + threadIdx.x;
  const int e  = g & (ED - 1);
  const int bc = g >> 11;
  const int b  = bc >> 6;
  const int c  = bc & (CH - 1);
  const size_t rowbase = (size_t)b * 1024 + (size_t)c * LC;

  __shared__ float4 sBC[LC][8];
  if (threadIdx.x < LC * 8) {
    const int row = threadIdx.x >> 3, q = threadIdx.x & 7;
    sBC[row][q] = ((const float4*)(dbc + (rowbase + row) * 96 + RLOW))[q];
  }
  __syncthreads();

  float Aen[NST];
  {
    const float4* Ap = (const float4*)(A_log + (size_t)e * NST);
#pragma unroll
    for (int q = 0; q < 4; ++q) {
      float4 v = Ap[q];
      Aen[q*4+0] = -__expf(v.x); Aen[q*4+1] = -__expf(v.y);
      Aen[q*4+2] = -__expf(v.z); Aen[q*4+3] = -__expf(v.w);
    }
  }

  float dtv[LC], xcv[LC];
#pragma unroll
  for (int i = 0; i < LC; ++i) dtv[i] = dt[(rowbase + i) * ED + e];
#pragma unroll
  for (int i = 0; i < LC; ++i) xcv[i] = b2f(xcb[(rowbase + i) * ED + e]);

  float h[NST];
  {
    const float4* Hp = (const float4*)(hst + ((size_t)(b * ED + e) * CH + c) * NST);
#pragma unroll
    for (int q = 0; q < 4; ++q) {
      float4 v = Hp[q];
      h[q*4+0]=v.x; h[q*4+1]=v.y; h[q*4+2]=v.z; h[q*4+3]=v.w;
    }
  }

  const float De = Dp[e];
  for (int i = 0; i < LC; ++i) {
    const size_t rr = rowbase + i;
    float Bv[NST], Cv[NST];
#pragma unroll
    for (int q = 0; q < 4; ++q) {
      float4 v = sBC[i][q];
      Bv[q*4+0]=v.x; Bv[q*4+1]=v.y; Bv[q*4+2]=v.z; Bv[q*4+3]=v.w;
      float4 w = sBC[i][q + 4];
      Cv[q*4+0]=w.x; Cv[q*4+1]=w.y; Cv[q*4+2]=w.z; Cv[q*4+3]=w.w;
    }
    const float dx = dtv[i] * xcv[i];
    float y = 0.f;
#pragma unroll
    for (int n = 0; n < NST; ++n) {
      const float dA = __expf(dtv[i] * Aen[n]);
      h[n] = fmaf(dA, h[n], dx * Bv[n]);
      y = fmaf(Cv[n], h[n], y);
    }
    y = fmaf(De, xcv[i], y);
    const float zf = b2f(xzb[rr * (2 * ED) + ED + e]);
    ygb[rr * ED + e] = f2b(y * silu_(zf));
  }
}

extern "C" void kernel_launch(void* const* d_in, const int* in_sizes, int n_in,
                              void* d_out, int out_size, void* d_ws, size_t ws_size,
                              hipStream_t stream) {
  const float* x         = (const float*)d_in[0];
  const float* in_w      = (const float*)d_in[1];
  const float* in_b      = (const float*)d_in[2];
  const float* conv_w    = (const float*)d_in[3];
  const float* conv_b    = (const float*)d_in[4];
  const float* xproj_w   = (const float*)d_in[5];
  const float* dtproj_w  = (const float*)d_in[6];
  const float* dtproj_b  = (const float*)d_in[7];
  const float* A_log     = (const float*)d_in[8];
  const float* D_param   = (const float*)d_in[9];
  const float* outproj_w = (const float*)d_in[10];
  float* out = (float*)d_out;

  float* ws    = (float*)d_ws;
  float* dbc   = ws;                  //    196,608 f
  float* dtb   = dbc   + 196608;      //  4,194,304 f
  float* aprod = dtb   + 4194304;     //  4,194,304 f
  float* bfin  = aprod + 4194304;     //  4,194,304 f
  float* par   = bfin  + 4194304;     //  3,145,728 f (SK*DBCN)
  unsigned short* xzb  = (unsigned short*)(par + 3145728); // 8,388,608 us
  unsigned short* xb   = xzb  + 8388608;                   // 2,097,152 us
  unsigned short* iwb  = xb   + 2097152;                   // 4,194,304 us
  unsigned short* owb  = iwb  + 4194304;                   // 2,097,152 us
  unsigned short* xpwb = owb  + 2097152;                   //   262,144 us
  unsigned short* xcb  = xpwb + 262144;                    // 4,194,304 us
  unsigned short* ygb  = xcb  + 4194304;                   // 4,194,304 us
  // total ~115 MB

  const dim3 blk(256);

  // 0) convert inputs/weights to bf16
  cvt_bf16_k<<<dim3(2097152 / 4 / 256), blk, 0, stream>>>(x, xb, 2097152 / 4);
  cvt_bf16_k<<<dim3(4194304 / 4 / 256), blk, 0, stream>>>(in_w, iwb, 4194304 / 4);
  cvt_bf16_k<<<dim3(2097152 / 4 / 256), blk, 0, stream>>>(outproj_w, owb, 2097152 / 4);
  cvt_pad_xpw_k<<<dim3(262144 / 4 / 256), blk, 0, stream>>>(xproj_w, xpwb);

  // 1) xz = x @ in_proj_w^T + b  -> bf16 (2048 x 4096, K=1024)
  gemm_bf16<128, 128, true><<<dim3(BL / 128, 4096 / 128), blk, 0, stream>>>(
      xb, iwb, in_b, xzb, 2 * ED, 2 * ED, DIM, DIM, 0);

  // 2) xc = silu(conv(xz[:, :ED]) + cb) -> bf16
  conv_silu_k<<<dim3((BL * (ED / 4)) / 256), blk, 0, stream>>>(
      xzb, conv_w, conv_b, xcb);

  // 3) dbc = xc @ x_proj_w^T  (2048 x 96, K=2048), split-K x16 + reduce
  gemm_bf16<128, 128, false><<<dim3(BL / 128, 1, SK), blk, 0, stream>>>(
      xcb, xpwb, nullptr, par, 96, 96, ED / SK, ED, DBCN);
  reduce_dbc_k<<<dim3(DBCN / 4 / 256), blk, 0, stream>>>(par, dbc);

  // 4) dt = softplus(dbc[:, :64] @ dt_proj_w^T + dt_proj_b)  f32
  gemm_nt<1><<<dim3(BL / 64, ED / 64), blk, 0, stream>>>(
      dbc, 96, dtproj_w, RLOW, dtproj_b, dtb, ED, ED, RLOW);

  // 5) chunked scan
  scan_phase1<<<dim3((2 * CH * ED) / 256), blk, 0, stream>>>(
      dtb, xcb, dbc, A_log, aprod, bfin);
  scan_phase2<<<dim3((2 * ED) / 4), blk, 0, stream>>>(aprod, bfin);
  scan_phase3<<<dim3((2 * CH * ED) / 256), blk, 0, stream>>>(
      dtb, xcb, dbc, A_log, D_param, xzb, bfin, ygb);

  // 6) out = yg @ out_proj_w^T -> f32 (2048 x 1024, K=2048)
  gemm_bf16<64, 64, false><<<dim3(BL / 64, 1024 / 64), blk, 0, stream>>>(
      ygb, owb, nullptr, out, DIM, DIM, ED, ED, 0);
}

// Round 10
// 217.530 us; speedup vs baseline: 5.1279x; 1.0682x over previous
//
#include <hip/hip_runtime.h>
#include <cstddef>

// ---------------------------------------------------------------------------
// Mamba block forward. B=2, L=1024, D=1024, ED=2048, N=16, R=64, K=4. BL=2048.
// Round 10: fix reader row-group factor (wr*FM+m, wc*FN+n) in dbuf BK=64 GEMM.
// ---------------------------------------------------------------------------

#define BL   2048
#define DIM  1024
#define ED   2048
#define NST  16
#define RLOW 64
#define CH   64
#define LC   16
#define SK   16        // K-splits for x_proj
#define DBCN 196608    // BL*96

typedef __attribute__((ext_vector_type(4))) float   f32x4;
typedef __attribute__((ext_vector_type(8))) __bf16  bf16x8;
typedef __attribute__((ext_vector_type(8))) unsigned short us8;

__device__ __forceinline__ float silu_(float x) {
  return x / (1.f + __expf(-x));
}

__device__ __forceinline__ unsigned short f2b(float x) {
  union { float f; unsigned int u; } v; v.f = x;
  unsigned int r = v.u + 0x7FFFu + ((v.u >> 16) & 1u);   // RNE
  return (unsigned short)(r >> 16);
}

__device__ __forceinline__ float b2f(unsigned short u) {
  union { unsigned int i; float f; } v; v.i = (unsigned int)u << 16; return v.f;
}

__device__ __forceinline__ f32x4 mfma_bf16(us8 a, us8 b, f32x4 c) {
  return __builtin_amdgcn_mfma_f32_16x16x32_bf16(
      __builtin_bit_cast(bf16x8, a), __builtin_bit_cast(bf16x8, b), c, 0, 0, 0);
}

#define GLOAD_LDS16(gaddr, laddr)                                              \
  __builtin_amdgcn_global_load_lds(                                            \
      (const __attribute__((address_space(1))) unsigned int*)(gaddr),          \
      (__attribute__((address_space(3))) unsigned int*)(laddr), 16, 0, 0)

// ---------------- bf16 MFMA GEMM, double-buffered, BK=64 --------------------
// C[M,N] = A[M,K]bf16 @ W[N,K]bf16^T (+bias). OBF: bf16 out else f32.
// LDS tile layout: 16-row groups of 2048 B; within a group, (row,kch) sits at
// byte (kch>>2)*1024 + ((kch&3)*16 + row)*16, so a wave's fragment read for
// k-half h is groupbase + h*1024 + lane*16 (sequential, conflict-free).
// Stager: thread tid of issue j fetches global row j*32+((tid>>7)<<4|(tid&15)),
// k-chunk (tid>>4)&7; its gload_lds dest (ab + j*4096 + (tid>>6)*1024 +
// lane*16) lands exactly at that layout slot (derivation R9->R10).
template <int BM, int BN, bool OBF>
__global__ __launch_bounds__(256) void gemm_bf16(
    const unsigned short* __restrict__ A,
    const unsigned short* __restrict__ W,
    const float* __restrict__ bias,
    void* __restrict__ Cp, int ldc, int Nout, int Kloop, int lda, int sstride)
{
  constexpr int BK     = 64;
  constexpr int FM     = BM / 32;
  constexpr int FN     = BN / 32;
  constexpr int NLA    = BM / 32;              // 4KB issues per A tile
  constexpr int NLW    = BN / 32;
  constexpr int ABYTES = BM * BK * 2;
  constexpr int WBYTES = BN * BK * 2;
  __shared__ char smem[2 * (ABYTES + WBYTES)];

  const int tid  = threadIdx.x;
  const int w    = tid >> 6;
  const int lane = tid & 63;
  const int wr   = w >> 1, wc = w & 1;
  const int bm   = blockIdx.x * BM;
  const int bn   = blockIdx.y * BN;
  const int kb   = blockIdx.z * Kloop;

  f32x4 acc[FM][FN];
#pragma unroll
  for (int m = 0; m < FM; ++m)
#pragma unroll
    for (int n = 0; n < FN; ++n) acc[m][n] = (f32x4){0.f, 0.f, 0.f, 0.f};

  const int srow = ((tid >> 7) << 4) | (tid & 15);   // row within 32-row issue
  const int kch  = (tid >> 4) & 7;                   // 8-elem chunk 0..7
  const int wofs = (tid >> 6) * 1024;                // wave's LDS slice

  const unsigned short* Ag = A + (size_t)(bm + srow) * lda + kb + kch * 8;
  const unsigned short* Wg = W + (size_t)(bn + srow) * lda + kb + kch * 8;

#define STAGE(cur, k0)                                                         \
  {                                                                            \
    char* ab = smem + (cur) * (ABYTES + WBYTES);                               \
    char* wb = ab + ABYTES;                                                    \
    _Pragma("unroll")                                                          \
    for (int j = 0; j < NLA; ++j)                                              \
      GLOAD_LDS16(Ag + (size_t)(j * 32) * lda + (k0), ab + j * 4096 + wofs);   \
    _Pragma("unroll")                                                          \
    for (int j = 0; j < NLW; ++j)                                              \
      GLOAD_LDS16(Wg + (size_t)(j * 32) * lda + (k0), wb + j * 4096 + wofs);   \
  }

  STAGE(0, 0);
  int cur = 0;
  const int NT = Kloop / BK;
  for (int t = 0; t < NT; ++t) {
    __syncthreads();                       // drains buf[cur] loads
    if (t + 1 < NT) STAGE(cur ^ 1, (t + 1) * BK);

    const char* ab = smem + cur * (ABYTES + WBYTES);
    const char* wb = ab + ABYTES;
    us8 af[FM][2], wf[FN][2];
#pragma unroll
    for (int m = 0; m < FM; ++m)
#pragma unroll
      for (int h = 0; h < 2; ++h)
        af[m][h] = *(const us8*)(ab + (wr * FM + m) * 2048 + h * 1024 + lane * 16);
#pragma unroll
    for (int n = 0; n < FN; ++n)
#pragma unroll
      for (int h = 0; h < 2; ++h)
        wf[n][h] = *(const us8*)(wb + (wc * FN + n) * 2048 + h * 1024 + lane * 16);
#pragma unroll
    for (int h = 0; h < 2; ++h)
#pragma unroll
      for (int m = 0; m < FM; ++m)
#pragma unroll
        for (int n = 0; n < FN; ++n)
          acc[m][n] = mfma_bf16(af[m][h], wf[n][h], acc[m][n]);
    cur ^= 1;
  }
#undef STAGE

  // C/D layout: col=lane&15, row=(lane>>4)*4+r  [m89-verified]
  const int rbase = (lane >> 4) * 4;
  float* Cf = (float*)Cp + (size_t)blockIdx.z * sstride;
#pragma unroll
  for (int m = 0; m < FM; ++m) {
#pragma unroll
    for (int n = 0; n < FN; ++n) {
      const int col = bn + wc * (BN / 2) + n * 16 + (lane & 15);
      if (col < Nout) {
        const float bv = bias ? bias[col] : 0.f;
#pragma unroll
        for (int r = 0; r < 4; ++r) {
          const int row = bm + wr * (BM / 2) + m * 16 + rbase + r;
          const float v = acc[m][n][r] + bv;
          if (OBF) ((unsigned short*)Cp)[(size_t)row * ldc + col] = f2b(v);
          else     Cf[(size_t)row * ldc + col] = v;
        }
      }
    }
  }
}

// dbc = sum over SK split-K partials
__global__ __launch_bounds__(256) void reduce_dbc_k(
    const float* __restrict__ par, float* __restrict__ dbc)
{
  const int i = blockIdx.x * 256 + threadIdx.x;
  float4 s = ((const float4*)par)[i];
#pragma unroll
  for (int sk = 1; sk < SK; ++sk) {
    float4 v = ((const float4*)(par + (size_t)sk * DBCN))[i];
    s.x += v.x; s.y += v.y; s.z += v.z; s.w += v.w;
  }
  ((float4*)dbc)[i] = s;
}

// out = par0 + par1 (out_proj split-K x2), 2048x1024 f32
__global__ __launch_bounds__(256) void reduce_out_k(
    const float* __restrict__ par, float* __restrict__ out)
{
  const int i = blockIdx.x * 256 + threadIdx.x;   // 524288 threads
  float4 a = ((const float4*)par)[i];
  float4 b = ((const float4*)(par + 2097152))[i];
  a.x += b.x; a.y += b.y; a.z += b.z; a.w += b.w;
  ((float4*)out)[i] = a;
}

// ---------------- fp32 GEMM (dt_proj, K=64) ---------------------------------
template <int ACT>
__global__ __launch_bounds__(256) void gemm_nt(
    const float* __restrict__ A, int lda,
    const float* __restrict__ W, int ldw,
    const float* __restrict__ bias,
    float* __restrict__ C, int ldc,
    int N, int K)
{
  __shared__ float As[16][64];
  __shared__ float Ws[16][64];
  const int tid = threadIdx.x;
  const int bm = blockIdx.x * 64;
  const int bn = blockIdx.y * 64;
  const int tx = tid & 15;
  const int ty = tid >> 4;
  const int srow = tid >> 2;
  const int scg  = (tid & 3) * 4;

  float acc[4][4] = {};
  const float* Aptr = A + (size_t)(bm + srow) * lda + scg;
  const bool   wok  = (bn + srow) < N;
  const float* Wptr = W + (size_t)(bn + srow) * ldw + scg;

  for (int k0 = 0; k0 < K; k0 += 16) {
    float4 av = *(const float4*)(Aptr + k0);
    float4 wv = make_float4(0.f, 0.f, 0.f, 0.f);
    if (wok) wv = *(const float4*)(Wptr + k0);
    __syncthreads();
    As[scg + 0][srow] = av.x; As[scg + 1][srow] = av.y;
    As[scg + 2][srow] = av.z; As[scg + 3][srow] = av.w;
    Ws[scg + 0][srow] = wv.x; Ws[scg + 1][srow] = wv.y;
    Ws[scg + 2][srow] = wv.z; Ws[scg + 3][srow] = wv.w;
    __syncthreads();
#pragma unroll
    for (int k = 0; k < 16; ++k) {
      float4 a4 = *(const float4*)&As[k][ty * 4];
      float4 w4 = *(const float4*)&Ws[k][tx * 4];
      float a_[4] = {a4.x, a4.y, a4.z, a4.w};
      float w_[4] = {w4.x, w4.y, w4.z, w4.w};
#pragma unroll
      for (int i = 0; i < 4; ++i)
#pragma unroll
        for (int j = 0; j < 4; ++j)
          acc[i][j] += a_[i] * w_[j];
    }
  }

#pragma unroll
  for (int i = 0; i < 4; ++i) {
    const int row = bm + ty * 4 + i;
#pragma unroll
    for (int j = 0; j < 4; ++j) {
      const int col = bn + tx * 4 + j;
      if (col < N) {
        float v = acc[i][j];
        if (bias) v += bias[col];
        if (ACT == 1) v = (v > 20.f) ? v : log1pf(__expf(v));
        C[(size_t)row * ldc + col] = v;
      }
    }
  }
}

// ---------------- fused converts --------------------------------------------
__global__ __launch_bounds__(256) void cvt_all_k(
    const float* __restrict__ x, const float* __restrict__ inw,
    const float* __restrict__ ow, const float* __restrict__ xpw,
    unsigned short* __restrict__ xb, unsigned short* __restrict__ iwb,
    unsigned short* __restrict__ owb, unsigned short* __restrict__ xpwb)
{
  const int i = blockIdx.x * 256 + threadIdx.x;
  const float* src; unsigned short* dst; int j;
  if (i < 524288)       { src = x;   dst = xb;  j = i; }
  else if (i < 1572864) { src = inw; dst = iwb; j = i - 524288; }
  else if (i < 2097152) { src = ow;  dst = owb; j = i - 1572864; }
  else {
    j = i - 2097152;                    // xpw pad path
    const int idx = j * 4;
    ushort4 o = {0, 0, 0, 0};
    if ((idx >> 11) < 96) {
      float4 v = *(const float4*)(xpw + idx);
      o.x = f2b(v.x); o.y = f2b(v.y); o.z = f2b(v.z); o.w = f2b(v.w);
    }
    *(ushort4*)(xpwb + idx) = o;
    return;
  }
  float4 v = ((const float4*)src)[j];
  ushort4 o;
  o.x = f2b(v.x); o.y = f2b(v.y); o.z = f2b(v.z); o.w = f2b(v.w);
  ((ushort4*)dst)[j] = o;
}

// ---------------- conv + SiLU (bf16 in, bf16 out) ---------------------------
__global__ __launch_bounds__(256) void conv_silu_k(
    const unsigned short* __restrict__ xzb, const float* __restrict__ cw,
    const float* __restrict__ cb, unsigned short* __restrict__ xcb)
{
  const int idx = blockIdx.x * 256 + threadIdx.x;
  const int row = idx >> 9;
  const int e   = (idx & 511) * 4;
  const int l   = row & 1023;
  const unsigned short* base = xzb + (size_t)(row - l) * (2 * ED) + e;

  float4 cbv = *(const float4*)(cb + e);
  float a0 = cbv.x, a1 = cbv.y, a2 = cbv.z, a3 = cbv.w;
#pragma unroll
  for (int k = 0; k < 4; ++k) {
    const int ls = l - 3 + k;
    if (ls >= 0) {
      ushort4 u = *(const ushort4*)(base + (size_t)ls * (2 * ED));
      a0 += cw[(size_t)(e + 0) * 4 + k] * b2f(u.x);
      a1 += cw[(size_t)(e + 1) * 4 + k] * b2f(u.y);
      a2 += cw[(size_t)(e + 2) * 4 + k] * b2f(u.z);
      a3 += cw[(size_t)(e + 3) * 4 + k] * b2f(u.w);
    }
  }
  ushort4 o;
  o.x = f2b(silu_(a0)); o.y = f2b(silu_(a1));
  o.z = f2b(silu_(a2)); o.w = f2b(silu_(a3));
  *(ushort4*)(xcb + (size_t)row * ED + e) = o;
}

// ---------------- chunked selective scan ------------------------------------
__global__ __launch_bounds__(256, 4) void scan_phase1(
    const float* __restrict__ dt, const unsigned short* __restrict__ xcb,
    const float* __restrict__ dbc, const float* __restrict__ A_log,
    float* __restrict__ aprod_o, float* __restrict__ bfin_o)
{
  const int g  = blockIdx.x * 256 + threadIdx.x;
  const int e  = g & (ED - 1);
  const int bc = g >> 11;
  const int b  = bc >> 6;
  const int c  = bc & (CH - 1);
  const size_t rowbase = (size_t)b * 1024 + (size_t)c * LC;

  __shared__ float4 sB[LC][4];
  if (threadIdx.x < LC * 4) {
    const int row = threadIdx.x >> 2, q = threadIdx.x & 3;
    sB[row][q] = ((const float4*)(dbc + (rowbase + row) * 96 + RLOW))[q];
  }
  __syncthreads();

  float Aen[NST];
  {
    const float4* Ap = (const float4*)(A_log + (size_t)e * NST);
#pragma unroll
    for (int q = 0; q < 4; ++q) {
      float4 v = Ap[q];
      Aen[q*4+0] = -__expf(v.x); Aen[q*4+1] = -__expf(v.y);
      Aen[q*4+2] = -__expf(v.z); Aen[q*4+3] = -__expf(v.w);
    }
  }

  float dtv[LC], dxv[LC];
#pragma unroll
  for (int i = 0; i < LC; ++i) dtv[i] = dt[(rowbase + i) * ED + e];
#pragma unroll
  for (int i = 0; i < LC; ++i)
    dxv[i] = dtv[i] * b2f(xcb[(rowbase + i) * ED + e]);

  float h[NST], ap[NST];
#pragma unroll
  for (int n = 0; n < NST; ++n) { h[n] = 0.f; ap[n] = 1.f; }

  for (int i = 0; i < LC; ++i) {
    float Bv[NST];
#pragma unroll
    for (int q = 0; q < 4; ++q) {
      float4 v = sB[i][q];
      Bv[q*4+0]=v.x; Bv[q*4+1]=v.y; Bv[q*4+2]=v.z; Bv[q*4+3]=v.w;
    }
#pragma unroll
    for (int n = 0; n < NST; ++n) {
      const float dA = __expf(dtv[i] * Aen[n]);
      ap[n] *= dA;
      h[n] = fmaf(dA, h[n], dxv[i] * Bv[n]);
    }
  }

  const size_t obase = ((size_t)(b * ED + e) * CH + c) * NST;
  float4* ao = (float4*)(aprod_o + obase);
  float4* bo = (float4*)(bfin_o + obase);
#pragma unroll
  for (int q = 0; q < 4; ++q) {
    ao[q] = make_float4(ap[q*4+0], ap[q*4+1], ap[q*4+2], ap[q*4+3]);
    bo[q] = make_float4(h[q*4+0],  h[q*4+1],  h[q*4+2],  h[q*4+3]);
  }
}

__global__ __launch_bounds__(256) void scan_phase2(
    const float* __restrict__ aprod, float* __restrict__ bfin)
{
  const int be   = blockIdx.x * 4 + (threadIdx.x >> 6);
  const int lane = threadIdx.x & 63;
  const size_t base = (size_t)be * CH * NST;

  float Aa[NST], Bb[NST];
  {
    const float4* ap4 = (const float4*)(aprod + base);
    const float4* bp4 = (const float4*)(bfin + base);
#pragma unroll
    for (int q = 0; q < 4; ++q) {
      float4 v = ap4[lane * 4 + q];
      Aa[q*4+0]=v.x; Aa[q*4+1]=v.y; Aa[q*4+2]=v.z; Aa[q*4+3]=v.w;
      float4 w = bp4[lane * 4 + q];
      Bb[q*4+0]=w.x; Bb[q*4+1]=w.y; Bb[q*4+2]=w.z; Bb[q*4+3]=w.w;
    }
  }

#pragma unroll
  for (int d = 1; d < 64; d <<= 1) {
#pragma unroll
    for (int r = 0; r < NST; ++r) {
      const float aP = __shfl_up(Aa[r], d);
      const float bP = __shfl_up(Bb[r], d);
      if (lane >= d) {
        Bb[r] = fmaf(Aa[r], bP, Bb[r]);
        Aa[r] *= aP;
      }
    }
  }

#pragma unroll
  for (int r = 0; r < NST; ++r) {
    const float hs = __shfl_up(Bb[r], 1);
    Bb[r] = (lane == 0) ? 0.f : hs;
  }

  float4* ob4 = (float4*)(bfin + base);
#pragma unroll
  for (int q = 0; q < 4; ++q)
    ob4[lane * 4 + q] = make_float4(Bb[q*4+0], Bb[q*4+1], Bb[q*4+2], Bb[q*4+3]);
}

__global__ __launch_bounds__(256, 4) void scan_phase3(
    const float* __restrict__ dt, const unsigned short* __restrict__ xcb,
    const float* __restrict__ dbc, const float* __restrict__ A_log,
    const float* __restrict__ Dp, const unsigned short* __restrict__ xzb,
    const float* __restrict__ hst, unsigned short* __restrict__ ygb)
{
  const int g  = blockIdx.x * 256 + threadIdx.x;
  const int e  = g & (ED - 1);
  const int bc = g >> 11;
  const int b  = bc >> 6;
  const int c  = bc & (CH - 1);
  const size_t rowbase = (size_t)b * 1024 + (size_t)c * LC;

  __shared__ float4 sBC[LC][8];
  if (threadIdx.x < LC * 8) {
    const int row = threadIdx.x >> 3, q = threadIdx.x & 7;
    sBC[row][q] = ((const float4*)(dbc + (rowbase + row) * 96 + RLOW))[q];
  }
  __syncthreads();

  float Aen[NST];
  {
    const float4* Ap = (const float4*)(A_log + (size_t)e * NST);
#pragma unroll
    for (int q = 0; q < 4; ++q) {
      float4 v = Ap[q];
      Aen[q*4+0] = -__expf(v.x); Aen[q*4+1] = -__expf(v.y);
      Aen[q*4+2] = -__expf(v.z); Aen[q*4+3] = -__expf(v.w);
    }
  }

  float dtv[LC], xcv[LC];
#pragma unroll
  for (int i = 0; i < LC; ++i) dtv[i] = dt[(rowbase + i) * ED + e];
#pragma unroll
  for (int i = 0; i < LC; ++i) xcv[i] = b2f(xcb[(rowbase + i) * ED + e]);

  float h[NST];
  {
    const float4* Hp = (const float4*)(hst + ((size_t)(b * ED + e) * CH + c) * NST);
#pragma unroll
    for (int q = 0; q < 4; ++q) {
      float4 v = Hp[q];
      h[q*4+0]=v.x; h[q*4+1]=v.y; h[q*4+2]=v.z; h[q*4+3]=v.w;
    }
  }

  const float De = Dp[e];
  for (int i = 0; i < LC; ++i) {
    const size_t rr = rowbase + i;
    float Bv[NST], Cv[NST];
#pragma unroll
    for (int q = 0; q < 4; ++q) {
      float4 v = sBC[i][q];
      Bv[q*4+0]=v.x; Bv[q*4+1]=v.y; Bv[q*4+2]=v.z; Bv[q*4+3]=v.w;
      float4 w = sBC[i][q + 4];
      Cv[q*4+0]=w.x; Cv[q*4+1]=w.y; Cv[q*4+2]=w.z; Cv[q*4+3]=w.w;
    }
    const float dx = dtv[i] * xcv[i];
    float y = 0.f;
#pragma unroll
    for (int n = 0; n < NST; ++n) {
      const float dA = __expf(dtv[i] * Aen[n]);
      h[n] = fmaf(dA, h[n], dx * Bv[n]);
      y = fmaf(Cv[n], h[n], y);
    }
    y = fmaf(De, xcv[i], y);
    const float zf = b2f(xzb[rr * (2 * ED) + ED + e]);
    ygb[rr * ED + e] = f2b(y * silu_(zf));
  }
}

extern "C" void kernel_launch(void* const* d_in, const int* in_sizes, int n_in,
                              void* d_out, int out_size, void* d_ws, size_t ws_size,
                              hipStream_t stream) {
  const float* x         = (const float*)d_in[0];
  const float* in_w      = (const float*)d_in[1];
  const float* in_b      = (const float*)d_in[2];
  const float* conv_w    = (const float*)d_in[3];
  const float* conv_b    = (const float*)d_in[4];
  const float* xproj_w   = (const float*)d_in[5];
  const float* dtproj_w  = (const float*)d_in[6];
  const float* dtproj_b  = (const float*)d_in[7];
  const float* A_log     = (const float*)d_in[8];
  const float* D_param   = (const float*)d_in[9];
  const float* outproj_w = (const float*)d_in[10];
  float* out = (float*)d_out;

  float* ws    = (float*)d_ws;
  float* dbc   = ws;                  //    196,608 f
  float* dtb   = dbc   + 196608;      //  4,194,304 f
  float* aprod = dtb   + 4194304;     //  4,194,304 f (reused as out_proj partials)
  float* bfin  = aprod + 4194304;     //  4,194,304 f
  float* parx  = bfin  + 4194304;     //  3,145,728 f (SK*DBCN)
  unsigned short* xzb  = (unsigned short*)(parx + 3145728); // 8,388,608 us
  unsigned short* xb   = xzb  + 8388608;                    // 2,097,152 us
  unsigned short* iwb  = xb   + 2097152;                    // 4,194,304 us
  unsigned short* owb  = iwb  + 4194304;                    // 2,097,152 us
  unsigned short* xpwb = owb  + 2097152;                    //   262,144 us
  unsigned short* xcb  = xpwb + 262144;                     // 4,194,304 us
  unsigned short* ygb  = xcb  + 4194304;                    // 4,194,304 us
  float* paro  = aprod;               // out_proj partials (aprod dead post-scan)

  const dim3 blk(256);

  // 0) all bf16 converts in one launch (2,162,688 float4-threads)
  cvt_all_k<<<dim3(2162688 / 256), blk, 0, stream>>>(
      x, in_w, outproj_w, xproj_w, xb, iwb, owb, xpwb);

  // 1) xz = x @ in_proj_w^T + b  -> bf16 (2048 x 4096, K=1024)
  gemm_bf16<128, 128, true><<<dim3(BL / 128, 4096 / 128), blk, 0, stream>>>(
      xb, iwb, in_b, xzb, 2 * ED, 2 * ED, DIM, DIM, 0);

  // 2) xc = silu(conv(xz[:, :ED]) + cb) -> bf16
  conv_silu_k<<<dim3((BL * (ED / 4)) / 256), blk, 0, stream>>>(
      xzb, conv_w, conv_b, xcb);

  // 3) dbc = xc @ x_proj_w^T  (2048 x 96, K=2048), split-K x16 + reduce
  gemm_bf16<128, 128, false><<<dim3(BL / 128, 1, SK), blk, 0, stream>>>(
      xcb, xpwb, nullptr, parx, 96, 96, ED / SK, ED, DBCN);
  reduce_dbc_k<<<dim3(DBCN / 4 / 256), blk, 0, stream>>>(parx, dbc);

  // 4) dt = softplus(dbc[:, :64] @ dt_proj_w^T + dt_proj_b)  f32
  gemm_nt<1><<<dim3(BL / 64, ED / 64), blk, 0, stream>>>(
      dbc, 96, dtproj_w, RLOW, dtproj_b, dtb, ED, ED, RLOW);

  // 5) chunked scan
  scan_phase1<<<dim3((2 * CH * ED) / 256), blk, 0, stream>>>(
      dtb, xcb, dbc, A_log, aprod, bfin);
  scan_phase2<<<dim3((2 * ED) / 4), blk, 0, stream>>>(aprod, bfin);
  scan_phase3<<<dim3((2 * CH * ED) / 256), blk, 0, stream>>>(
      dtb, xcb, dbc, A_log, D_param, xzb, bfin, ygb);

  // 6) out = yg @ out_proj_w^T  (2048 x 1024, K=2048), split-K x2 + reduce
  gemm_bf16<64, 128, false><<<dim3(BL / 64, 1024 / 128, 2), blk, 0, stream>>>(
      ygb, owb, nullptr, paro, DIM, DIM, ED / 2, ED, 2097152);
  reduce_out_k<<<dim3(2097152 / 4 / 256), blk, 0, stream>>>(paro, out);
}